// Round 7
// baseline (598.284 us; speedup 1.0000x reference)
//
#include <hip/hip_runtime.h>
#include <hip/hip_bf16.h>

typedef __hip_bfloat16 bf16;
typedef unsigned long long ull;

#define BB 4
#define NN 2048
#define CCH 128
#define DDM 128
#define KNB 16
#define HHD 64
#define AAD 512
#define PP (BB*NN)

typedef __attribute__((ext_vector_type(8))) short short8;
typedef __attribute__((ext_vector_type(16))) float f32x16;

__device__ __forceinline__ float b2f(bf16 x) { return __bfloat162float(x); }
__device__ __forceinline__ bf16 f2b(float x) { return __float2bfloat16(x); }

__device__ __forceinline__ float ldany(const void* p, size_t i, int f32) {
  return f32 ? ((const float*)p)[i] : __bfloat162float(((const bf16*)p)[i]);
}

__device__ __forceinline__ long pack4(float a, float b, float c, float d) {
  union { bf16 h[4]; long l; } u;
  u.h[0] = f2b(a); u.h[1] = f2b(b); u.h[2] = f2b(c); u.h[3] = f2b(d);
  return u.l;
}
__device__ __forceinline__ void unpack4(long l, float* o) {
  union { bf16 h[4]; long l; } u; u.l = l;
  o[0] = b2f(u.h[0]); o[1] = b2f(u.h[1]); o[2] = b2f(u.h[2]); o[3] = b2f(u.h[3]);
}

__device__ __forceinline__ short8 ldfrag(const bf16* base, int row, int stride, int k0, int hl) {
  const bf16* p = base + (size_t)row * stride + k0 + (hl << 3);
  union { short8 v; long l[2]; } u;
  u.l[0] = *(const long*)p;
  u.l[1] = *(const long*)(p + 4);
  return u.v;
}

__device__ __forceinline__ f32x16 MFMA(short8 a, short8 b, f32x16 c) {
  return __builtin_amdgcn_mfma_f32_32x32x16_bf16(a, b, c, 0, 0, 0);
}

struct PtrArr { const void* p[36]; int n[36]; };
struct CvtTab { int src[16]; int off[16]; int n[16]; int isb[16]; };

// ---------- dtype sniffer ----------
__global__ __launch_bounds__(256) void sniff_kern(PtrArr pa, int* __restrict__ flags) {
  int t = blockIdx.x;
  const bf16* x = (const bf16*)pa.p[t];
  int n = pa.n[t]; if (n > 4096) n = 4096;
  __shared__ int cnt;
  if (threadIdx.x == 0) cnt = 0;
  __syncthreads();
  int c = 0;
  for (int i = threadIdx.x; i < n; i += 256) {
    float v = fabsf(__bfloat162float(x[i]));
    if (v == 0.f || (v >= 1e-6f && v <= 1024.f)) c++;
  }
  atomicAdd(&cnt, c);
  __syncthreads();
  if (threadIdx.x == 0) flags[t] = (cnt >= (n * 7) / 8) ? 0 : 1;
}

// ---------- convert GEMM weights/biases into bf16 arena + fp32 bias arena ----------
__global__ __launch_bounds__(256) void wcvt_kern(PtrArr pa, CvtTab tab,
                                                 const int* __restrict__ flags,
                                                 bf16* __restrict__ warena,
                                                 float* __restrict__ barena) {
  int e = blockIdx.y;
  int i = blockIdx.x * 256 + threadIdx.x;
  if (i >= tab.n[e]) return;
  float v = ldany(pa.p[tab.src[e]], i, flags[tab.src[e]]);
  if (tab.isb[e]) barena[tab.off[e] + i] = v;
  else warena[tab.off[e] + i] = f2b(v);
}

// ---------- transpose (B,C,N) raw -> token-major (P, ldd) bf16 ----------
__global__ __launch_bounds__(256) void tr_in_kern(const void* __restrict__ src,
                                                  const int* __restrict__ flags, int fIdx,
                                                  bf16* __restrict__ dst,
                                                  int C, int ldd, int coff) {
  __shared__ float tile[64][65];
  const int f32 = flags[fIdx];
  int b = blockIdx.z, n0 = blockIdx.x * 64, c0 = blockIdx.y * 64;
  int tx = threadIdx.x & 63, ty = threadIdx.x >> 6;
  for (int r = ty; r < 64; r += 4)
    tile[r][tx] = ldany(src, (size_t)(b * C + c0 + r) * NN + n0 + tx, f32);
  __syncthreads();
  for (int r = ty; r < 64; r += 4)
    dst[(size_t)(b * NN + n0 + r) * ldd + coff + c0 + tx] = __float2bfloat16(tile[tx][r]);
}

// ---------- coords (B,dd,N) raw -> (P,4) fp32 ----------
__global__ __launch_bounds__(256) void tr_coords_kern(const void* __restrict__ src,
                                                      const int* __restrict__ flags, int fIdx,
                                                      float* __restrict__ dst, int dd) {
  const int f32 = flags[fIdx];
  int i = blockIdx.x * 256 + threadIdx.x;
  if (i >= PP * 4) return;
  int p = i >> 2, j = i & 3;
  int b = p >> 11, n = p & (NN - 1);
  dst[i] = (j < dd) ? ldany(src, (size_t)(b * dd + j) * NN + n, f32) : 0.f;
}

// ---------- MFMA GEMM: out[p][o] = act(X[p]·W[o] + b[o] (+ add[p][o])) ----------
__global__ __launch_bounds__(256) void gemm_kern(
    const bf16* __restrict__ X, int ldx, int K,
    const bf16* __restrict__ Wb, const float* __restrict__ bias,
    const bf16* __restrict__ add, bf16* __restrict__ out, int relu) {
  __shared__ __attribute__((aligned(16))) bf16 XT[64 * 260];
  int tid = threadIdx.x, lane = tid & 63, wv = tid >> 6;
  int hl = lane >> 5, cA = lane & 31;
  int p0 = blockIdx.x * 64;
  int SK = K + 4;
  int kc = K >> 3;
  for (int c = tid; c < 64 * kc; c += 256) {
    int r = c / kc, col = (c % kc) << 3;
    *(float4*)&XT[r * SK + col] = *(const float4*)&X[(size_t)(p0 + r) * ldx + col];
  }
  __syncthreads();
  int o0 = wv * 32;
  f32x16 acc[2];
#pragma unroll
  for (int r = 0; r < 16; ++r) {
    int o = o0 + (r & 3) + 8 * (r >> 2) + 4 * hl;
    float bv = bias[o];
    acc[0][r] = bv; acc[1][r] = bv;
  }
  for (int ks = 0; ks < (K >> 4); ++ks) {
    short8 af = ldfrag(Wb, o0 + cA, K, ks * 16, hl);
    short8 b0 = ldfrag(XT, cA, SK, ks * 16, hl);
    short8 b1 = ldfrag(XT, 32 + cA, SK, ks * 16, hl);
    acc[0] = MFMA(af, b0, acc[0]);
    acc[1] = MFMA(af, b1, acc[1]);
  }
#pragma unroll
  for (int t = 0; t < 2; ++t) {
    int m = p0 + t * 32 + cA;
#pragma unroll
    for (int q = 0; q < 4; ++q) {
      int ob = o0 + 8 * q + 4 * hl;
      float v[4] = {acc[t][4*q+0], acc[t][4*q+1], acc[t][4*q+2], acc[t][4*q+3]};
      if (add) {
        float av[4];
        unpack4(*(const long*)(add + (size_t)m * 128 + ob), av);
        v[0] += av[0]; v[1] += av[1]; v[2] += av[2]; v[3] += av[3];
      }
      if (relu) {
        v[0] = fmaxf(v[0], 0.f); v[1] = fmaxf(v[1], 0.f);
        v[2] = fmaxf(v[2], 0.f); v[3] = fmaxf(v[3], 0.f);
      }
      *(long*)(out + (size_t)m * 128 + ob) = pack4(v[0], v[1], v[2], v[3]);
    }
  }
}

// ---------- kNN: one wave per point, register top-16 + wave merge ----------
__global__ __launch_bounds__(256) void knn_kern(const float* __restrict__ coordsT,
                                                int* __restrict__ idxout) {
  __shared__ __attribute__((aligned(16))) float4 cds[NN];
  int tid = threadIdx.x, lane = tid & 63, wv = tid >> 6;
  int p0 = blockIdx.x * 4, b = p0 >> 11;
  for (int j = tid; j < NN; j += 256)
    cds[j] = *(const float4*)&coordsT[((size_t)(b << 11) + j) * 4];
  __syncthreads();
  int p = p0 + wv, n = p & (NN - 1);
  float4 cc = cds[n];
  float sqi = __fadd_rn(__fadd_rn(__fmul_rn(cc.x, cc.x), __fmul_rn(cc.y, cc.y)),
                        __fmul_rn(cc.z, cc.z));
  ull t[16];
#pragma unroll
  for (int i = 0; i < 16; ++i) t[i] = ~0ull;
  for (int s = 0; s < 32; ++s) {
    int j = (s << 6) | lane;
    float4 q = cds[j];
    float sqj = __fadd_rn(__fadd_rn(__fmul_rn(q.x, q.x), __fmul_rn(q.y, q.y)),
                          __fmul_rn(q.z, q.z));
    float dt  = __fadd_rn(__fadd_rn(__fmul_rn(cc.x, q.x), __fmul_rn(cc.y, q.y)),
                          __fmul_rn(cc.z, q.z));
    float d2 = __fsub_rn(__fadd_rn(sqi, sqj), __fmul_rn(2.f, dt));
    unsigned u = __float_as_uint(d2);
    u = (u & 0x80000000u) ? ~u : (u | 0x80000000u);
    ull key = ((ull)u << 32) | (unsigned)j;
    if (key < t[15]) {
      t[15] = key;
#pragma unroll
      for (int i = 15; i > 0; --i) {
        ull lo = t[i - 1] < t[i] ? t[i - 1] : t[i];
        ull hi = t[i - 1] < t[i] ? t[i] : t[i - 1];
        t[i - 1] = lo; t[i] = hi;
      }
    }
  }
  for (int r = 0; r < KNB; ++r) {
    ull h = t[0];
    ull m = h;
#pragma unroll
    for (int off = 1; off < 64; off <<= 1) {
      ull o = __shfl_xor(m, off);
      m = o < m ? o : m;
    }
    if (lane == 0) idxout[(size_t)p * KNB + r] = (int)(m & 0xffffffffu);
    if (h == m) {
#pragma unroll
      for (int i = 0; i < 15; ++i) t[i] = t[i + 1];
      t[15] = ~0ull;
    }
  }
}

// ---------- weight-image prep for attn ----------
__global__ __launch_bounds__(256) void prep_kern(
    const void* cw1, const void* cb1, const void* cw2, const void* cb2,
    const void* aw1, const void* ab1, const void* aw2, const void* ab2,
    const int* __restrict__ flags, int cIdx, int aIdx, int dd,
    bf16* __restrict__ w1img, bf16* __restrict__ w2img, bf16* __restrict__ cw2img,
    float* __restrict__ fb) {
  int i = blockIdx.x * 256 + threadIdx.x;
  const int fcw1 = flags[cIdx], fcb1 = flags[cIdx + 1];
  const int fcw2 = flags[cIdx + 2], fcb2 = flags[cIdx + 3];
  const int faw1 = flags[aIdx], fab1 = flags[aIdx + 1];
  const int faw2 = flags[aIdx + 2], fab2 = flags[aIdx + 3];
  float* ab1f = fb;          // 512
  float* ab2f = fb + 512;    // 128
  float* cb1f = fb + 640;    // 64
  float* cb2f = fb + 704;    // 128
  float* cw1f = fb + 832;    // 192
  if (i < 65536) {                       // w1img: [h_glob 512][132]
    int hg = i >> 7, c = i & 127;
    w1img[(size_t)hg * 132 + c] = f2b(ldany(aw1, i, faw1));
  } else if (i < 131072) {               // w2img: [ac*128+o][132] col=h_local
    int j = i - 65536;
    int o = j >> 9, hh = j & 511;
    int ac = hh >> 7, hloc = hh & 127;
    w2img[(size_t)(ac * 128 + o) * 132 + hloc] = f2b(ldany(aw2, j, faw2));
  } else if (i < 139264) {               // cw2img: [o 128][68]
    int j = i - 131072;
    int o = j >> 6, h = j & 63;
    cw2img[o * 68 + h] = f2b(ldany(cw2, j, fcw2));
  } else if (i < 139776) {
    int j = i - 139264; ab1f[j] = ldany(ab1, j, fab1);
  } else if (i < 139904) {
    int j = i - 139776; ab2f[j] = ldany(ab2, j, fab2);
  } else if (i < 139968) {
    int j = i - 139904; cb1f[j] = ldany(cb1, j, fcb1);
  } else if (i < 140096) {
    int j = i - 139968; cb2f[j] = ldany(cb2, j, fcb2);
  } else if (i < 140288) {
    int j = i - 140096;
    int h = j / 3, c = j % 3;
    cw1f[j] = (c < dd) ? ldany(cw1, h * dd + c, fcw1) : 0.f;
  }
}

// ---------- MFMA fused kNN attention: 4 points / 64 tokens, 256 threads ----------
// LDS 36096 B -> 4 WG/CU x 4 waves = 16 waves/CU (4/SIMD, 128-VGPR budget, no spills).
// Wave wv: m-tile = (wv&1), o-strips = {64*(wv>>1), 64*(wv>>1)+32}.
#define SMEM_BYTES 36096
__global__ __launch_bounds__(256, 4) void attn_mfma(
    const bf16* __restrict__ centerT, const bf16* __restrict__ gatherT,
    const float* __restrict__ coordsT, const bf16* __restrict__ vfeatT,
    const int* __restrict__ idx,
    const bf16* __restrict__ w1img, const bf16* __restrict__ w2img,
    const bf16* __restrict__ cw2img, const float* __restrict__ fb,
    bf16* __restrict__ aggT) {
  extern __shared__ char smem[];
  bf16* XS  = (bf16*)(smem);            // [64][132]
  bf16* HT  = (bf16*)(smem + 16896);    // [64][132]
  bf16* HC  = HT;                       // [64][68] aliases HT (dead before chunk 0)
  bf16* CFE = (bf16*)(smem + 33792);    // [4][128]
  bf16* VF  = (bf16*)(smem + 34816);    // [4][128]
  int*  NID = (int*)(smem + 35840);     // [64]
  const float* ab1f = fb;
  const float* ab2f = fb + 512;
  const float* cb1f = fb + 640;
  const float* cb2f = fb + 704;
  const float* cw1f = fb + 832;

  int tid = threadIdx.x, lane = tid & 63, wv = tid >> 6;
  int hl = lane >> 5, cA = lane & 31;
  int P0 = blockIdx.x * 4, b = P0 >> 11;

  if (tid < 64) NID[tid] = (b << 11) + idx[(size_t)(P0 + (tid >> 4)) * KNB + (tid & 15)];
  for (int i = tid; i < 512; i += 256) {
    int g = i >> 7, d = i & 127;
    CFE[i] = centerT[(size_t)(P0 + g) * 128 + d];
    VF[i]  = vfeatT[(size_t)(P0 + g) * 128 + d];
  }
  __syncthreads();

  // phase 1: coord hidden HC + XS base (= cfe - gathered); 4 threads per token
  {
    int m = tid >> 2, sub = tid & 3;
    float4 ccd = *(const float4*)&coordsT[(size_t)(P0 + (m >> 4)) * 4];
    float4 nbd = *(const float4*)&coordsT[(size_t)NID[m] * 4];
    float r0 = ccd.x - nbd.x, r1 = ccd.y - nbd.y, r2 = ccd.z - nbd.z;
    int h0 = sub * 16;
    for (int hh = h0; hh < h0 + 16; hh += 4) {
      float a0 = fmaxf(cb1f[hh+0] + cw1f[(hh+0)*3]*r0 + cw1f[(hh+0)*3+1]*r1 + cw1f[(hh+0)*3+2]*r2, 0.f);
      float a1 = fmaxf(cb1f[hh+1] + cw1f[(hh+1)*3]*r0 + cw1f[(hh+1)*3+1]*r1 + cw1f[(hh+1)*3+2]*r2, 0.f);
      float a2 = fmaxf(cb1f[hh+2] + cw1f[(hh+2)*3]*r0 + cw1f[(hh+2)*3+1]*r1 + cw1f[(hh+2)*3+2]*r2, 0.f);
      float a3 = fmaxf(cb1f[hh+3] + cw1f[(hh+3)*3]*r0 + cw1f[(hh+3)*3+1]*r1 + cw1f[(hh+3)*3+2]*r2, 0.f);
      *(long*)&HC[m * 68 + hh] = pack4(a0, a1, a2, a3);
    }
    const bf16* grow = gatherT + (size_t)NID[m] * 128 + sub * 32;
    const bf16* crow = CFE + ((m >> 4) << 7) + sub * 32;
    for (int j = 0; j < 32; j += 4) {
      float gv[4], cv[4];
      unpack4(*(const long*)(grow + j), gv);
      unpack4(*(const long*)(crow + j), cv);
      *(long*)&XS[m * 132 + sub * 32 + j] =
          pack4(cv[0] - gv[0], cv[1] - gv[1], cv[2] - gv[2], cv[3] - gv[3]);
    }
  }
  __syncthreads();

  int os0 = (wv >> 1) * 64;    // first o-strip (second = os0+32)
  int mt0 = (wv & 1) * 32;     // token tile

  // phase 2: emb GEMM (C_e[o][m] = cw2 @ HC + cb2), RMW into XS
  {
    f32x16 eacc[2];
#pragma unroll
    for (int s = 0; s < 2; ++s)
#pragma unroll
      for (int r = 0; r < 16; ++r) {
        int o = os0 + s * 32 + (r & 3) + 8 * (r >> 2) + 4 * hl;
        eacc[s][r] = cb2f[o];
      }
    for (int k0 = 0; k0 < 64; k0 += 16) {
      short8 b0 = ldfrag(HC, mt0 + cA, 68, k0, hl);
      short8 a0 = ldfrag(cw2img, os0 + cA, 68, k0, hl);
      short8 a1 = ldfrag(cw2img, os0 + 32 + cA, 68, k0, hl);
      eacc[0] = MFMA(a0, b0, eacc[0]);
      eacc[1] = MFMA(a1, b0, eacc[1]);
    }
    int m = mt0 + cA;
#pragma unroll
    for (int s = 0; s < 2; ++s)
#pragma unroll
      for (int q = 0; q < 4; ++q) {
        int ob = os0 + s * 32 + 8 * q + 4 * hl;
        bf16* px = &XS[m * 132 + ob];
        float xv[4];
        unpack4(*(long*)px, xv);
        *(long*)px = pack4(xv[0] + eacc[s][4*q+0], xv[1] + eacc[s][4*q+1],
                           xv[2] + eacc[s][4*q+2], xv[3] + eacc[s][4*q+3]);
      }
  }
  __syncthreads();

  // logits accumulator (bias-init)
  f32x16 acc2[2];
#pragma unroll
  for (int s = 0; s < 2; ++s)
#pragma unroll
    for (int r = 0; r < 16; ++r) {
      int o = os0 + s * 32 + (r & 3) + 8 * (r >> 2) + 4 * hl;
      acc2[s][r] = ab2f[o];
    }

  // chunk loop: 4 x 128 hidden; W fragments straight from global images
  for (int ac = 0; ac < 4; ++ac) {
    const bf16* w1c = w1img + (size_t)ac * 16896;
    const bf16* w2c = w2img + (size_t)ac * 16896;
    // GEMM1: H[h][m] = relu(W1 @ X + ab1)
    f32x16 acc1[2];
#pragma unroll
    for (int s = 0; s < 2; ++s)
#pragma unroll
      for (int r = 0; r < 16; ++r) {
        int h = os0 + s * 32 + (r & 3) + 8 * (r >> 2) + 4 * hl;
        acc1[s][r] = ab1f[ac * 128 + h];
      }
#pragma unroll
    for (int ks = 0; ks < 8; ++ks) {
      short8 b0 = ldfrag(XS, mt0 + cA, 132, ks * 16, hl);
      short8 a0 = ldfrag(w1c, os0 + cA, 132, ks * 16, hl);
      short8 a1 = ldfrag(w1c, os0 + 32 + cA, 132, ks * 16, hl);
      acc1[0] = MFMA(a0, b0, acc1[0]);
      acc1[1] = MFMA(a1, b0, acc1[1]);
    }
    __syncthreads();  // prior chunk's HT reads (and phase-2 HC reads) complete
    {
      int m = mt0 + cA;
#pragma unroll
      for (int s = 0; s < 2; ++s)
#pragma unroll
        for (int q = 0; q < 4; ++q) {
          int hb = os0 + s * 32 + 8 * q + 4 * hl;
          *(long*)&HT[m * 132 + hb] =
              pack4(fmaxf(acc1[s][4*q+0], 0.f), fmaxf(acc1[s][4*q+1], 0.f),
                    fmaxf(acc1[s][4*q+2], 0.f), fmaxf(acc1[s][4*q+3], 0.f));
        }
    }
    __syncthreads();  // HT complete
    // GEMM2: logits[o][m] += W2 @ H
#pragma unroll
    for (int ks = 0; ks < 8; ++ks) {
      short8 b0 = ldfrag(HT, mt0 + cA, 132, ks * 16, hl);
      short8 a0 = ldfrag(w2c, os0 + cA, 132, ks * 16, hl);
      short8 a1 = ldfrag(w2c, os0 + 32 + cA, 132, ks * 16, hl);
      acc2[0] = MFMA(a0, b0, acc2[0]);
      acc2[1] = MFMA(a1, b0, acc2[1]);
    }
  }

  // softmax-one over kk (16-lane groups) + aggregation; probs reuse acc2 in place
  {
    int m = mt0 + cA;
    int g = m >> 4;
#pragma unroll
    for (int s = 0; s < 2; ++s) {
#pragma unroll
      for (int r = 0; r < 16; ++r) {
        float x = acc2[s][r];
        float mx = x;
        mx = fmaxf(mx, __shfl_xor(mx, 1, 16));
        mx = fmaxf(mx, __shfl_xor(mx, 2, 16));
        mx = fmaxf(mx, __shfl_xor(mx, 4, 16));
        mx = fmaxf(mx, __shfl_xor(mx, 8, 16));
        float e = __expf(x - mx);
        float sm = e;
        sm += __shfl_xor(sm, 1, 16);
        sm += __shfl_xor(sm, 2, 16);
        sm += __shfl_xor(sm, 4, 16);
        sm += __shfl_xor(sm, 8, 16);
        acc2[s][r] = e / (1.f + sm);
      }
#pragma unroll
      for (int q = 0; q < 4; ++q) {
        int ob = os0 + s * 32 + 8 * q + 4 * hl;
        float xv[4], gv[4], vv[4], cv[4];
        unpack4(*(long*)&XS[m * 132 + ob], xv);
        unpack4(*(const long*)(gatherT + (size_t)NID[m] * 128 + ob), gv);
        unpack4(*(long*)&VF[(g << 7) + ob], vv);
        unpack4(*(long*)&CFE[(g << 7) + ob], cv);
        float p0 = acc2[s][4*q+0] * (vv[0] - cv[0] + xv[0] + gv[0]);
        float p1 = acc2[s][4*q+1] * (vv[1] - cv[1] + xv[1] + gv[1]);
        float p2 = acc2[s][4*q+2] * (vv[2] - cv[2] + xv[2] + gv[2]);
        float p3 = acc2[s][4*q+3] * (vv[3] - cv[3] + xv[3] + gv[3]);
#pragma unroll
        for (int sh = 1; sh < 16; sh <<= 1) {
          p0 += __shfl_xor(p0, sh, 16);
          p1 += __shfl_xor(p1, sh, 16);
          p2 += __shfl_xor(p2, sh, 16);
          p3 += __shfl_xor(p3, sh, 16);
        }
        if ((lane & 15) == 0)
          *(long*)(aggT + (size_t)(P0 + g) * 128 + ob) = pack4(p0, p1, p2, p3);
      }
    }
  }
}

// ---------- token-major bf16 (P,128) -> (B,128,N) output ----------
__global__ __launch_bounds__(256) void out_kern(const bf16* __restrict__ yT,
                                                void* __restrict__ outp,
                                                const int* __restrict__ flags, int ofIdx) {
  __shared__ float tile[64][65];
  const int f32 = flags[ofIdx];
  int b = blockIdx.z, n0 = blockIdx.x * 64, c0 = blockIdx.y * 64;
  int tx = threadIdx.x & 63, ty = threadIdx.x >> 6;
  for (int r = ty; r < 64; r += 4)
    tile[r][tx] = b2f(yT[(size_t)(b * NN + n0 + r) * 128 + c0 + tx]);
  __syncthreads();
  for (int r = ty; r < 64; r += 4) {
    size_t oi = (size_t)(b * CCH + c0 + r) * NN + n0 + tx;
    float v = tile[tx][r];
    if (f32) ((float*)outp)[oi] = v;
    else ((bf16*)outp)[oi] = __float2bfloat16(v);
  }
}

extern "C" void kernel_launch(void* const* d_in, const int* in_sizes, int n_in,
                              void* d_out, int out_size, void* d_ws, size_t ws_size,
                              hipStream_t stream) {
  // workspace layout
  int* flags = (int*)d_ws;
  bf16* catT = (bf16*)((float*)d_ws + 64);        // P x 256
  bf16* v0   = catT + (size_t)PP * 256;
  bf16* kT   = v0 + (size_t)PP * 128;
  bf16* qT   = kT + (size_t)PP * 128;
  bf16* sE   = qT + (size_t)PP * 128;             // vT, then value2
  bf16* sF   = sE + (size_t)PP * 128;             // tmp, agg1, agg2
  bf16* sG   = sF + (size_t)PP * 128;             // shortb, val1, yT
  float* xyzT = (float*)(sG + (size_t)PP * 128);  // P x 4
  float* posT = xyzT + (size_t)PP * 4;
  int* idxb = (int*)(posT + (size_t)PP * 4);      // P x 16
  bf16* w1i1 = (bf16*)(idxb + (size_t)PP * KNB);  // 4*128*132
  bf16* w2i1 = w1i1 + 67584;
  bf16* cw2i1 = w2i1 + 67584;                     // 128*68
  bf16* w1i2 = cw2i1 + 8704;
  bf16* w2i2 = w1i2 + 67584;
  bf16* cw2i2 = w2i2 + 67584;
  float* fb1 = (float*)(cw2i2 + 8704);            // 1024 floats
  float* fb2 = fb1 + 1024;
  bf16* warena = (bf16*)(fb2 + 1024);             // 163840 bf16
  float* barena = (float*)(warena + 163840);      // 1024 fp32

  PtrArr pa;
  for (int i = 0; i < 36; ++i) { pa.p[i] = d_in[i]; pa.n[i] = in_sizes[i]; }
  sniff_kern<<<dim3(36), 256, 0, stream>>>(pa, flags);

  CvtTab tab;
  int wsrc[8] = {4, 8, 6, 10, 12, 14, 32, 34};
  int woff[8] = {0, 32768, 65536, 81920, 98304, 114688, 131072, 147456};
  int wn[8]   = {32768, 32768, 16384, 16384, 16384, 16384, 16384, 16384};
  int bsrc[8] = {5, 9, 7, 11, 13, 15, 33, 35};
  for (int e = 0; e < 8; ++e) {
    tab.src[e] = wsrc[e]; tab.off[e] = woff[e]; tab.n[e] = wn[e]; tab.isb[e] = 0;
    tab.src[8 + e] = bsrc[e]; tab.off[8 + e] = e * 128; tab.n[8 + e] = 128; tab.isb[8 + e] = 1;
  }
  wcvt_kern<<<dim3(128, 16), 256, 0, stream>>>(pa, tab, flags, warena, barena);

  prep_kern<<<dim3(548), 256, 0, stream>>>(d_in[16], d_in[17], d_in[18], d_in[19],
                                           d_in[24], d_in[25], d_in[26], d_in[27],
                                           flags, 16, 24, 3, w1i1, w2i1, cw2i1, fb1);
  prep_kern<<<dim3(548), 256, 0, stream>>>(d_in[20], d_in[21], d_in[22], d_in[23],
                                           d_in[28], d_in[29], d_in[30], d_in[31],
                                           flags, 20, 28, 2, w1i2, w2i2, cw2i2, fb2);

  dim3 trg(32, 2, 4);
  tr_in_kern<<<trg, 256, 0, stream>>>(d_in[2], flags, 2, catT, 128, 256, 0);
  tr_in_kern<<<trg, 256, 0, stream>>>(d_in[3], flags, 3, catT, 128, 256, 128);
  tr_coords_kern<<<dim3(128), 256, 0, stream>>>(d_in[0], flags, 0, xyzT, 3);
  tr_coords_kern<<<dim3(128), 256, 0, stream>>>(d_in[1], flags, 1, posT, 2);

  dim3 gg(PP / 64);
  // MLP_Res frontend
  gemm_kern<<<gg, 256, 0, stream>>>(catT, 256, 256, warena + 0,      barena + 0,   nullptr, sF, 1);
  gemm_kern<<<gg, 256, 0, stream>>>(catT, 256, 256, warena + 32768,  barena + 128, nullptr, sG, 0);
  gemm_kern<<<gg, 256, 0, stream>>>(sF,   128, 128, warena + 65536,  barena + 256, sG,      v0, 0);
  // k, q, v
  gemm_kern<<<gg, 256, 0, stream>>>(catT,       256, 128, warena + 81920,  barena + 384, nullptr, kT, 0);
  gemm_kern<<<gg, 256, 0, stream>>>(catT + 128, 256, 128, warena + 98304,  barena + 512, nullptr, qT, 0);
  gemm_kern<<<gg, 256, 0, stream>>>(v0,         128, 128, warena + 114688, barena + 640, nullptr, sE, 0);

  hipFuncSetAttribute((const void*)attn_mfma, hipFuncAttributeMaxDynamicSharedMemorySize, SMEM_BYTES);

  // block 1 (xyz): center=k, gathered=q, vfeat=v
  knn_kern<<<dim3(PP / 4), 256, 0, stream>>>(xyzT, idxb);
  attn_mfma<<<dim3(PP / 4), 256, SMEM_BYTES, stream>>>(kT, qT, xyzT, sE, idxb,
                                                       w1i1, w2i1, cw2i1, fb1, sF);
  gemm_kern<<<gg, 256, 0, stream>>>(sF, 128, 128, warena + 131072, barena + 768, v0, sG, 0);
  gemm_kern<<<gg, 256, 0, stream>>>(sG, 128, 128, warena + 114688, barena + 640, nullptr, sE, 0);
  // block 2 (pos): center=q, gathered=k, vfeat=value2
  knn_kern<<<dim3(PP / 4), 256, 0, stream>>>(posT, idxb);
  attn_mfma<<<dim3(PP / 4), 256, SMEM_BYTES, stream>>>(qT, kT, posT, sE, idxb,
                                                       w1i2, w2i2, cw2i2, fb2, sF);
  gemm_kern<<<gg, 256, 0, stream>>>(sF, 128, 128, warena + 147456, barena + 896, v0, sG, 0);
  out_kern<<<trg, 256, 0, stream>>>(sG, d_out, flags, 2);
}

// Round 8
// 544.624 us; speedup vs baseline: 1.0985x; 1.0985x over previous
//
#include <hip/hip_runtime.h>
#include <hip/hip_bf16.h>

typedef __hip_bfloat16 bf16;
typedef unsigned long long ull;

#define BB 4
#define NN 2048
#define CCH 128
#define DDM 128
#define KNB 16
#define HHD 64
#define AAD 512
#define PP (BB*NN)

typedef __attribute__((ext_vector_type(8))) short short8;
typedef __attribute__((ext_vector_type(16))) float f32x16;

__device__ __forceinline__ float b2f(bf16 x) { return __bfloat162float(x); }
__device__ __forceinline__ bf16 f2b(float x) { return __float2bfloat16(x); }

__device__ __forceinline__ float ldany(const void* p, size_t i, int f32) {
  return f32 ? ((const float*)p)[i] : __bfloat162float(((const bf16*)p)[i]);
}

__device__ __forceinline__ long pack4(float a, float b, float c, float d) {
  union { bf16 h[4]; long l; } u;
  u.h[0] = f2b(a); u.h[1] = f2b(b); u.h[2] = f2b(c); u.h[3] = f2b(d);
  return u.l;
}
__device__ __forceinline__ void unpack4(long l, float* o) {
  union { bf16 h[4]; long l; } u; u.l = l;
  o[0] = b2f(u.h[0]); o[1] = b2f(u.h[1]); o[2] = b2f(u.h[2]); o[3] = b2f(u.h[3]);
}

__device__ __forceinline__ short8 ldfrag(const bf16* base, int row, int stride, int k0, int hl) {
  const bf16* p = base + (size_t)row * stride + k0 + (hl << 3);
  union { short8 v; long l[2]; } u;
  u.l[0] = *(const long*)p;
  u.l[1] = *(const long*)(p + 4);
  return u.v;
}

__device__ __forceinline__ f32x16 MFMA(short8 a, short8 b, f32x16 c) {
  return __builtin_amdgcn_mfma_f32_32x32x16_bf16(a, b, c, 0, 0, 0);
}

struct PtrArr { const void* p[36]; int n[36]; };
struct CvtTab { int src[16]; int off[16]; int n[16]; int isb[16]; };

// ---------- dtype sniffer ----------
__global__ __launch_bounds__(256) void sniff_kern(PtrArr pa, int* __restrict__ flags) {
  int t = blockIdx.x;
  const bf16* x = (const bf16*)pa.p[t];
  int n = pa.n[t]; if (n > 4096) n = 4096;
  __shared__ int cnt;
  if (threadIdx.x == 0) cnt = 0;
  __syncthreads();
  int c = 0;
  for (int i = threadIdx.x; i < n; i += 256) {
    float v = fabsf(__bfloat162float(x[i]));
    if (v == 0.f || (v >= 1e-6f && v <= 1024.f)) c++;
  }
  atomicAdd(&cnt, c);
  __syncthreads();
  if (threadIdx.x == 0) flags[t] = (cnt >= (n * 7) / 8) ? 0 : 1;
}

// ---------- convert GEMM weights/biases into bf16 arena + fp32 bias arena ----------
__global__ __launch_bounds__(256) void wcvt_kern(PtrArr pa, CvtTab tab,
                                                 const int* __restrict__ flags,
                                                 bf16* __restrict__ warena,
                                                 float* __restrict__ barena) {
  int e = blockIdx.y;
  int i = blockIdx.x * 256 + threadIdx.x;
  if (i >= tab.n[e]) return;
  float v = ldany(pa.p[tab.src[e]], i, flags[tab.src[e]]);
  if (tab.isb[e]) barena[tab.off[e] + i] = v;
  else warena[tab.off[e] + i] = f2b(v);
}

// ---------- transpose (B,C,N) raw -> token-major (P, ldd) bf16 ----------
__global__ __launch_bounds__(256) void tr_in_kern(const void* __restrict__ src,
                                                  const int* __restrict__ flags, int fIdx,
                                                  bf16* __restrict__ dst,
                                                  int C, int ldd, int coff) {
  __shared__ float tile[64][65];
  const int f32 = flags[fIdx];
  int b = blockIdx.z, n0 = blockIdx.x * 64, c0 = blockIdx.y * 64;
  int tx = threadIdx.x & 63, ty = threadIdx.x >> 6;
  for (int r = ty; r < 64; r += 4)
    tile[r][tx] = ldany(src, (size_t)(b * C + c0 + r) * NN + n0 + tx, f32);
  __syncthreads();
  for (int r = ty; r < 64; r += 4)
    dst[(size_t)(b * NN + n0 + r) * ldd + coff + c0 + tx] = __float2bfloat16(tile[tx][r]);
}

// ---------- coords (B,dd,N) raw -> (P,4) fp32 ----------
__global__ __launch_bounds__(256) void tr_coords_kern(const void* __restrict__ src,
                                                      const int* __restrict__ flags, int fIdx,
                                                      float* __restrict__ dst, int dd) {
  const int f32 = flags[fIdx];
  int i = blockIdx.x * 256 + threadIdx.x;
  if (i >= PP * 4) return;
  int p = i >> 2, j = i & 3;
  int b = p >> 11, n = p & (NN - 1);
  dst[i] = (j < dd) ? ldany(src, (size_t)(b * dd + j) * NN + n, f32) : 0.f;
}

// ---------- MFMA GEMM: out[p][o] = act(X[p]·W[o] + b[o] (+ add[p][o])) ----------
__global__ __launch_bounds__(256) void gemm_kern(
    const bf16* __restrict__ X, int ldx, int K,
    const bf16* __restrict__ Wb, const float* __restrict__ bias,
    const bf16* __restrict__ add, bf16* __restrict__ out, int relu) {
  __shared__ __attribute__((aligned(16))) bf16 XT[64 * 260];
  int tid = threadIdx.x, lane = tid & 63, wv = tid >> 6;
  int hl = lane >> 5, cA = lane & 31;
  int p0 = blockIdx.x * 64;
  int SK = K + 4;
  int kc = K >> 3;
  for (int c = tid; c < 64 * kc; c += 256) {
    int r = c / kc, col = (c % kc) << 3;
    *(float4*)&XT[r * SK + col] = *(const float4*)&X[(size_t)(p0 + r) * ldx + col];
  }
  __syncthreads();
  int o0 = wv * 32;
  f32x16 acc[2];
#pragma unroll
  for (int r = 0; r < 16; ++r) {
    int o = o0 + (r & 3) + 8 * (r >> 2) + 4 * hl;
    float bv = bias[o];
    acc[0][r] = bv; acc[1][r] = bv;
  }
  for (int ks = 0; ks < (K >> 4); ++ks) {
    short8 af = ldfrag(Wb, o0 + cA, K, ks * 16, hl);
    short8 b0 = ldfrag(XT, cA, SK, ks * 16, hl);
    short8 b1 = ldfrag(XT, 32 + cA, SK, ks * 16, hl);
    acc[0] = MFMA(af, b0, acc[0]);
    acc[1] = MFMA(af, b1, acc[1]);
  }
#pragma unroll
  for (int t = 0; t < 2; ++t) {
    int m = p0 + t * 32 + cA;
#pragma unroll
    for (int q = 0; q < 4; ++q) {
      int ob = o0 + 8 * q + 4 * hl;
      float v[4] = {acc[t][4*q+0], acc[t][4*q+1], acc[t][4*q+2], acc[t][4*q+3]};
      if (add) {
        float av[4];
        unpack4(*(const long*)(add + (size_t)m * 128 + ob), av);
        v[0] += av[0]; v[1] += av[1]; v[2] += av[2]; v[3] += av[3];
      }
      if (relu) {
        v[0] = fmaxf(v[0], 0.f); v[1] = fmaxf(v[1], 0.f);
        v[2] = fmaxf(v[2], 0.f); v[3] = fmaxf(v[3], 0.f);
      }
      *(long*)(out + (size_t)m * 128 + ob) = pack4(v[0], v[1], v[2], v[3]);
    }
  }
}

// ---------- kNN: one wave per point, register top-16 + wave merge ----------
__global__ __launch_bounds__(256) void knn_kern(const float* __restrict__ coordsT,
                                                int* __restrict__ idxout) {
  __shared__ __attribute__((aligned(16))) float4 cds[NN];
  int tid = threadIdx.x, lane = tid & 63, wv = tid >> 6;
  int p0 = blockIdx.x * 4, b = p0 >> 11;
  for (int j = tid; j < NN; j += 256)
    cds[j] = *(const float4*)&coordsT[((size_t)(b << 11) + j) * 4];
  __syncthreads();
  int p = p0 + wv, n = p & (NN - 1);
  float4 cc = cds[n];
  float sqi = __fadd_rn(__fadd_rn(__fmul_rn(cc.x, cc.x), __fmul_rn(cc.y, cc.y)),
                        __fmul_rn(cc.z, cc.z));
  ull t[16];
#pragma unroll
  for (int i = 0; i < 16; ++i) t[i] = ~0ull;
  for (int s = 0; s < 32; ++s) {
    int j = (s << 6) | lane;
    float4 q = cds[j];
    float sqj = __fadd_rn(__fadd_rn(__fmul_rn(q.x, q.x), __fmul_rn(q.y, q.y)),
                          __fmul_rn(q.z, q.z));
    float dt  = __fadd_rn(__fadd_rn(__fmul_rn(cc.x, q.x), __fmul_rn(cc.y, q.y)),
                          __fmul_rn(cc.z, q.z));
    float d2 = __fsub_rn(__fadd_rn(sqi, sqj), __fmul_rn(2.f, dt));
    unsigned u = __float_as_uint(d2);
    u = (u & 0x80000000u) ? ~u : (u | 0x80000000u);
    ull key = ((ull)u << 32) | (unsigned)j;
    if (key < t[15]) {
      t[15] = key;
#pragma unroll
      for (int i = 15; i > 0; --i) {
        ull lo = t[i - 1] < t[i] ? t[i - 1] : t[i];
        ull hi = t[i - 1] < t[i] ? t[i] : t[i - 1];
        t[i - 1] = lo; t[i] = hi;
      }
    }
  }
  for (int r = 0; r < KNB; ++r) {
    ull h = t[0];
    ull m = h;
#pragma unroll
    for (int off = 1; off < 64; off <<= 1) {
      ull o = __shfl_xor(m, off);
      m = o < m ? o : m;
    }
    if (lane == 0) idxout[(size_t)p * KNB + r] = (int)(m & 0xffffffffu);
    if (h == m) {
#pragma unroll
      for (int i = 0; i < 15; ++i) t[i] = t[i + 1];
      t[15] = ~0ull;
    }
  }
}

// ---------- weight-image prep for attn ----------
__global__ __launch_bounds__(256) void prep_kern(
    const void* cw1, const void* cb1, const void* cw2, const void* cb2,
    const void* aw1, const void* ab1, const void* aw2, const void* ab2,
    const int* __restrict__ flags, int cIdx, int aIdx, int dd,
    bf16* __restrict__ w1img, bf16* __restrict__ w2img, bf16* __restrict__ cw2img,
    float* __restrict__ fb) {
  int i = blockIdx.x * 256 + threadIdx.x;
  const int fcw1 = flags[cIdx], fcb1 = flags[cIdx + 1];
  const int fcw2 = flags[cIdx + 2], fcb2 = flags[cIdx + 3];
  const int faw1 = flags[aIdx], fab1 = flags[aIdx + 1];
  const int faw2 = flags[aIdx + 2], fab2 = flags[aIdx + 3];
  float* ab1f = fb;          // 512
  float* ab2f = fb + 512;    // 128
  float* cb1f = fb + 640;    // 64
  float* cb2f = fb + 704;    // 128
  float* cw1f = fb + 832;    // 192
  if (i < 65536) {                       // w1img: [h_glob 512][132]
    int hg = i >> 7, c = i & 127;
    w1img[(size_t)hg * 132 + c] = f2b(ldany(aw1, i, faw1));
  } else if (i < 131072) {               // w2img: [ac*128+o][132] col=h_local
    int j = i - 65536;
    int o = j >> 9, hh = j & 511;
    int ac = hh >> 7, hloc = hh & 127;
    w2img[(size_t)(ac * 128 + o) * 132 + hloc] = f2b(ldany(aw2, j, faw2));
  } else if (i < 139264) {               // cw2img: [o 128][68]
    int j = i - 131072;
    int o = j >> 6, h = j & 63;
    cw2img[o * 68 + h] = f2b(ldany(cw2, j, fcw2));
  } else if (i < 139776) {
    int j = i - 139264; ab1f[j] = ldany(ab1, j, fab1);
  } else if (i < 139904) {
    int j = i - 139776; ab2f[j] = ldany(ab2, j, fab2);
  } else if (i < 139968) {
    int j = i - 139904; cb1f[j] = ldany(cb1, j, fcb1);
  } else if (i < 140096) {
    int j = i - 139968; cb2f[j] = ldany(cb2, j, fcb2);
  } else if (i < 140288) {
    int j = i - 140096;
    int h = j / 3, c = j % 3;
    cw1f[j] = (c < dd) ? ldany(cw1, h * dd + c, fcw1) : 0.f;
  }
}

// ---------- MFMA fused kNN attention: 8 points / 128 tokens per workgroup ----------
// Round-5 shape (72 KB LDS, 2 WG/CU) + rotating register prefetch of weight
// fragments: pf[ks] always holds the NEXT GEMM's A-fragment, giving each
// global weight load >= one full GEMM-loop of latency cover.
#define SMEM_BYTES 72192
__global__ __launch_bounds__(512, 4) void attn_mfma(
    const bf16* __restrict__ centerT, const bf16* __restrict__ gatherT,
    const float* __restrict__ coordsT, const bf16* __restrict__ vfeatT,
    const int* __restrict__ idx,
    const bf16* __restrict__ w1img, const bf16* __restrict__ w2img,
    const bf16* __restrict__ cw2img, const float* __restrict__ fb,
    bf16* __restrict__ aggT) {
  extern __shared__ char smem[];
  bf16* XS  = (bf16*)(smem);            // [128][132]
  bf16* HT  = (bf16*)(smem + 33792);    // [128][132]
  bf16* HC  = HT;                       // [128][68] aliases HT (dead before chunk 0)
  bf16* CFE = (bf16*)(smem + 67584);    // [8][128]
  bf16* VF  = (bf16*)(smem + 69632);    // [8][128]
  int*  NID = (int*)(smem + 71680);     // [128]
  const float* ab1f = fb;
  const float* ab2f = fb + 512;
  const float* cb1f = fb + 640;
  const float* cb2f = fb + 704;
  const float* cw1f = fb + 832;

  int tid = threadIdx.x, lane = tid & 63, wv = tid >> 6;
  int hl = lane >> 5, cA = lane & 31;
  int P0 = blockIdx.x * 8, b = P0 >> 11;

  if (tid < 128) NID[tid] = (b << 11) + idx[(size_t)(P0 + (tid >> 4)) * KNB + (tid & 15)];
  for (int i = tid; i < 1024; i += 512) {
    int g = i >> 7, d = i & 127;
    CFE[i] = centerT[(size_t)(P0 + g) * 128 + d];
    VF[i]  = vfeatT[(size_t)(P0 + g) * 128 + d];
  }
  __syncthreads();

  // phase 1: coord hidden HC + XS base (= cfe - gathered)
  {
    int m = tid >> 2, sub = tid & 3;
    float4 ccd = *(const float4*)&coordsT[(size_t)(P0 + (m >> 4)) * 4];
    float4 nbd = *(const float4*)&coordsT[(size_t)NID[m] * 4];
    float r0 = ccd.x - nbd.x, r1 = ccd.y - nbd.y, r2 = ccd.z - nbd.z;
    int h0 = sub * 16;
    for (int hh = h0; hh < h0 + 16; hh += 4) {
      float a0 = fmaxf(cb1f[hh+0] + cw1f[(hh+0)*3]*r0 + cw1f[(hh+0)*3+1]*r1 + cw1f[(hh+0)*3+2]*r2, 0.f);
      float a1 = fmaxf(cb1f[hh+1] + cw1f[(hh+1)*3]*r0 + cw1f[(hh+1)*3+1]*r1 + cw1f[(hh+1)*3+2]*r2, 0.f);
      float a2 = fmaxf(cb1f[hh+2] + cw1f[(hh+2)*3]*r0 + cw1f[(hh+2)*3+1]*r1 + cw1f[(hh+2)*3+2]*r2, 0.f);
      float a3 = fmaxf(cb1f[hh+3] + cw1f[(hh+3)*3]*r0 + cw1f[(hh+3)*3+1]*r1 + cw1f[(hh+3)*3+2]*r2, 0.f);
      *(long*)&HC[m * 68 + hh] = pack4(a0, a1, a2, a3);
    }
    const bf16* grow = gatherT + (size_t)NID[m] * 128 + sub * 32;
    const bf16* crow = CFE + ((m >> 4) << 7) + sub * 32;
    for (int j = 0; j < 32; j += 4) {
      float gv[4], cv[4];
      unpack4(*(const long*)(grow + j), gv);
      unpack4(*(const long*)(crow + j), cv);
      *(long*)&XS[m * 132 + sub * 32 + j] =
          pack4(cv[0] - gv[0], cv[1] - gv[1], cv[2] - gv[2], cv[3] - gv[3]);
    }
  }
  __syncthreads();

  int r0s = (wv & 3) * 32;     // output-row strip (o / h)
  int mt0 = (wv >> 2) * 64;    // token strip (2 tiles of 32)

  // preload chunk-0 W1 fragments (in flight across the emb GEMM)
  short8 pf[8];
#pragma unroll
  for (int ks = 0; ks < 8; ++ks)
    pf[ks] = ldfrag(w1img, r0s + cA, 132, ks * 16, hl);

  // phase 2: emb GEMM (C_e[o][m] = cw2 @ HC + cb2), RMW into XS
  {
    f32x16 eacc[2];
#pragma unroll
    for (int r = 0; r < 16; ++r) {
      int o = r0s + (r & 3) + 8 * (r >> 2) + 4 * hl;
      float bv = cb2f[o];
      eacc[0][r] = bv; eacc[1][r] = bv;
    }
    for (int k0 = 0; k0 < 64; k0 += 16) {
      short8 af = ldfrag(cw2img, r0s + cA, 68, k0, hl);   // global, L2-hot
      short8 b0 = ldfrag(HC, mt0 + cA, 68, k0, hl);
      short8 b1 = ldfrag(HC, mt0 + 32 + cA, 68, k0, hl);
      eacc[0] = MFMA(af, b0, eacc[0]);
      eacc[1] = MFMA(af, b1, eacc[1]);
    }
#pragma unroll
    for (int t = 0; t < 2; ++t) {
      int m = mt0 + t * 32 + cA;
#pragma unroll
      for (int q = 0; q < 4; ++q) {
        int ob = r0s + 8 * q + 4 * hl;
        bf16* px = &XS[m * 132 + ob];
        float xv[4];
        unpack4(*(long*)px, xv);
        *(long*)px = pack4(xv[0] + eacc[t][4*q+0], xv[1] + eacc[t][4*q+1],
                           xv[2] + eacc[t][4*q+2], xv[3] + eacc[t][4*q+3]);
      }
    }
  }
  __syncthreads();

  // logits accumulator (bias-init)
  f32x16 acc2[2];
#pragma unroll
  for (int r = 0; r < 16; ++r) {
    int o = r0s + (r & 3) + 8 * (r >> 2) + 4 * hl;
    float bv = ab2f[o];
    acc2[0][r] = bv; acc2[1][r] = bv;
  }

  // chunk loop: 4 x 128 hidden; pf[] rotates W1(chunk ac) -> W2(ac) -> W1(ac+1)
  for (int ac = 0; ac < 4; ++ac) {
    const bf16* w2c = w2img + (size_t)ac * 16896;
    const bf16* w1n = w1img + (size_t)((ac + 1) & 3) * 16896;
    // GEMM1: H[h][m] = relu(W1 @ X + ab1); prefetch W2 per iteration
    f32x16 acc1[2];
#pragma unroll
    for (int r = 0; r < 16; ++r) {
      int h = r0s + (r & 3) + 8 * (r >> 2) + 4 * hl;
      float bv = ab1f[ac * 128 + h];
      acc1[0][r] = bv; acc1[1][r] = bv;
    }
#pragma unroll
    for (int ks = 0; ks < 8; ++ks) {
      short8 af = pf[ks];
      short8 b0 = ldfrag(XS, mt0 + cA, 132, ks * 16, hl);
      short8 b1 = ldfrag(XS, mt0 + 32 + cA, 132, ks * 16, hl);
      pf[ks] = ldfrag(w2c, r0s + cA, 132, ks * 16, hl);
      acc1[0] = MFMA(af, b0, acc1[0]);
      acc1[1] = MFMA(af, b1, acc1[1]);
    }
    __syncthreads();  // prior chunk's HT reads (and phase-2 HC reads) complete
#pragma unroll
    for (int t = 0; t < 2; ++t) {
      int m = mt0 + t * 32 + cA;
#pragma unroll
      for (int q = 0; q < 4; ++q) {
        int hb = r0s + 8 * q + 4 * hl;
        *(long*)&HT[m * 132 + hb] =
            pack4(fmaxf(acc1[t][4*q+0], 0.f), fmaxf(acc1[t][4*q+1], 0.f),
                  fmaxf(acc1[t][4*q+2], 0.f), fmaxf(acc1[t][4*q+3], 0.f));
      }
    }
    __syncthreads();  // HT complete
    // GEMM2: logits[o][m] += W2 @ H; prefetch next chunk's W1 per iteration
#pragma unroll
    for (int ks = 0; ks < 8; ++ks) {
      short8 af = pf[ks];
      short8 b0 = ldfrag(HT, mt0 + cA, 132, ks * 16, hl);
      short8 b1 = ldfrag(HT, mt0 + 32 + cA, 132, ks * 16, hl);
      pf[ks] = ldfrag(w1n, r0s + cA, 132, ks * 16, hl);
      acc2[0] = MFMA(af, b0, acc2[0]);
      acc2[1] = MFMA(af, b1, acc2[1]);
    }
  }

  // softmax-one over kk (16-lane groups) + aggregation
#pragma unroll
  for (int t = 0; t < 2; ++t) {
    int m = mt0 + t * 32 + cA;
    int g = m >> 4;
    float a[16];
#pragma unroll
    for (int r = 0; r < 16; ++r) {
      float x = acc2[t][r];
      float mx = x;
      mx = fmaxf(mx, __shfl_xor(mx, 1, 16));
      mx = fmaxf(mx, __shfl_xor(mx, 2, 16));
      mx = fmaxf(mx, __shfl_xor(mx, 4, 16));
      mx = fmaxf(mx, __shfl_xor(mx, 8, 16));
      float e = __expf(x - mx);
      float s = e;
      s += __shfl_xor(s, 1, 16);
      s += __shfl_xor(s, 2, 16);
      s += __shfl_xor(s, 4, 16);
      s += __shfl_xor(s, 8, 16);
      a[r] = e / (1.f + s);
    }
#pragma unroll
    for (int q = 0; q < 4; ++q) {
      int ob = r0s + 8 * q + 4 * hl;
      float xv[4], gv[4], vv[4], cv[4];
      unpack4(*(long*)&XS[m * 132 + ob], xv);
      unpack4(*(const long*)(gatherT + (size_t)NID[m] * 128 + ob), gv);
      unpack4(*(long*)&VF[(g << 7) + ob], vv);
      unpack4(*(long*)&CFE[(g << 7) + ob], cv);
      float p0 = a[4*q+0] * (vv[0] - cv[0] + xv[0] + gv[0]);
      float p1 = a[4*q+1] * (vv[1] - cv[1] + xv[1] + gv[1]);
      float p2 = a[4*q+2] * (vv[2] - cv[2] + xv[2] + gv[2]);
      float p3 = a[4*q+3] * (vv[3] - cv[3] + xv[3] + gv[3]);
#pragma unroll
      for (int s = 1; s < 16; s <<= 1) {
        p0 += __shfl_xor(p0, s, 16);
        p1 += __shfl_xor(p1, s, 16);
        p2 += __shfl_xor(p2, s, 16);
        p3 += __shfl_xor(p3, s, 16);
      }
      if ((lane & 15) == 0)
        *(long*)(aggT + (size_t)(P0 + g) * 128 + ob) = pack4(p0, p1, p2, p3);
    }
  }
}

// ---------- token-major bf16 (P,128) -> (B,128,N) output ----------
__global__ __launch_bounds__(256) void out_kern(const bf16* __restrict__ yT,
                                                void* __restrict__ outp,
                                                const int* __restrict__ flags, int ofIdx) {
  __shared__ float tile[64][65];
  const int f32 = flags[ofIdx];
  int b = blockIdx.z, n0 = blockIdx.x * 64, c0 = blockIdx.y * 64;
  int tx = threadIdx.x & 63, ty = threadIdx.x >> 6;
  for (int r = ty; r < 64; r += 4)
    tile[r][tx] = b2f(yT[(size_t)(b * NN + n0 + r) * 128 + c0 + tx]);
  __syncthreads();
  for (int r = ty; r < 64; r += 4) {
    size_t oi = (size_t)(b * CCH + c0 + r) * NN + n0 + tx;
    float v = tile[tx][r];
    if (f32) ((float*)outp)[oi] = v;
    else ((bf16*)outp)[oi] = __float2bfloat16(v);
  }
}

extern "C" void kernel_launch(void* const* d_in, const int* in_sizes, int n_in,
                              void* d_out, int out_size, void* d_ws, size_t ws_size,
                              hipStream_t stream) {
  // workspace layout
  int* flags = (int*)d_ws;
  bf16* catT = (bf16*)((float*)d_ws + 64);        // P x 256
  bf16* v0   = catT + (size_t)PP * 256;
  bf16* kT   = v0 + (size_t)PP * 128;
  bf16* qT   = kT + (size_t)PP * 128;
  bf16* sE   = qT + (size_t)PP * 128;             // vT, then value2
  bf16* sF   = sE + (size_t)PP * 128;             // tmp, agg1, agg2
  bf16* sG   = sF + (size_t)PP * 128;             // shortb, val1, yT
  float* xyzT = (float*)(sG + (size_t)PP * 128);  // P x 4
  float* posT = xyzT + (size_t)PP * 4;
  int* idxb = (int*)(posT + (size_t)PP * 4);      // P x 16
  bf16* w1i1 = (bf16*)(idxb + (size_t)PP * KNB);  // 4*128*132
  bf16* w2i1 = w1i1 + 67584;
  bf16* cw2i1 = w2i1 + 67584;                     // 128*68
  bf16* w1i2 = cw2i1 + 8704;
  bf16* w2i2 = w1i2 + 67584;
  bf16* cw2i2 = w2i2 + 67584;
  float* fb1 = (float*)(cw2i2 + 8704);            // 1024 floats
  float* fb2 = fb1 + 1024;
  bf16* warena = (bf16*)(fb2 + 1024);             // 163840 bf16
  float* barena = (float*)(warena + 163840);      // 1024 fp32

  PtrArr pa;
  for (int i = 0; i < 36; ++i) { pa.p[i] = d_in[i]; pa.n[i] = in_sizes[i]; }
  sniff_kern<<<dim3(36), 256, 0, stream>>>(pa, flags);

  CvtTab tab;
  int wsrc[8] = {4, 8, 6, 10, 12, 14, 32, 34};
  int woff[8] = {0, 32768, 65536, 81920, 98304, 114688, 131072, 147456};
  int wn[8]   = {32768, 32768, 16384, 16384, 16384, 16384, 16384, 16384};
  int bsrc[8] = {5, 9, 7, 11, 13, 15, 33, 35};
  for (int e = 0; e < 8; ++e) {
    tab.src[e] = wsrc[e]; tab.off[e] = woff[e]; tab.n[e] = wn[e]; tab.isb[e] = 0;
    tab.src[8 + e] = bsrc[e]; tab.off[8 + e] = e * 128; tab.n[8 + e] = 128; tab.isb[8 + e] = 1;
  }
  wcvt_kern<<<dim3(128, 16), 256, 0, stream>>>(pa, tab, flags, warena, barena);

  prep_kern<<<dim3(548), 256, 0, stream>>>(d_in[16], d_in[17], d_in[18], d_in[19],
                                           d_in[24], d_in[25], d_in[26], d_in[27],
                                           flags, 16, 24, 3, w1i1, w2i1, cw2i1, fb1);
  prep_kern<<<dim3(548), 256, 0, stream>>>(d_in[20], d_in[21], d_in[22], d_in[23],
                                           d_in[28], d_in[29], d_in[30], d_in[31],
                                           flags, 20, 28, 2, w1i2, w2i2, cw2i2, fb2);

  dim3 trg(32, 2, 4);
  tr_in_kern<<<trg, 256, 0, stream>>>(d_in[2], flags, 2, catT, 128, 256, 0);
  tr_in_kern<<<trg, 256, 0, stream>>>(d_in[3], flags, 3, catT, 128, 256, 128);
  tr_coords_kern<<<dim3(128), 256, 0, stream>>>(d_in[0], flags, 0, xyzT, 3);
  tr_coords_kern<<<dim3(128), 256, 0, stream>>>(d_in[1], flags, 1, posT, 2);

  dim3 gg(PP / 64);
  // MLP_Res frontend
  gemm_kern<<<gg, 256, 0, stream>>>(catT, 256, 256, warena + 0,      barena + 0,   nullptr, sF, 1);
  gemm_kern<<<gg, 256, 0, stream>>>(catT, 256, 256, warena + 32768,  barena + 128, nullptr, sG, 0);
  gemm_kern<<<gg, 256, 0, stream>>>(sF,   128, 128, warena + 65536,  barena + 256, sG,      v0, 0);
  // k, q, v
  gemm_kern<<<gg, 256, 0, stream>>>(catT,       256, 128, warena + 81920,  barena + 384, nullptr, kT, 0);
  gemm_kern<<<gg, 256, 0, stream>>>(catT + 128, 256, 128, warena + 98304,  barena + 512, nullptr, qT, 0);
  gemm_kern<<<gg, 256, 0, stream>>>(v0,         128, 128, warena + 114688, barena + 640, nullptr, sE, 0);

  hipFuncSetAttribute((const void*)attn_mfma, hipFuncAttributeMaxDynamicSharedMemorySize, SMEM_BYTES);

  // block 1 (xyz): center=k, gathered=q, vfeat=v
  knn_kern<<<dim3(PP / 4), 256, 0, stream>>>(xyzT, idxb);
  attn_mfma<<<dim3(PP / 8), 512, SMEM_BYTES, stream>>>(kT, qT, xyzT, sE, idxb,
                                                       w1i1, w2i1, cw2i1, fb1, sF);
  gemm_kern<<<gg, 256, 0, stream>>>(sF, 128, 128, warena + 131072, barena + 768, v0, sG, 0);
  gemm_kern<<<gg, 256, 0, stream>>>(sG, 128, 128, warena + 114688, barena + 640, nullptr, sE, 0);
  // block 2 (pos): center=q, gathered=k, vfeat=value2
  knn_kern<<<dim3(PP / 4), 256, 0, stream>>>(posT, idxb);
  attn_mfma<<<dim3(PP / 8), 512, SMEM_BYTES, stream>>>(qT, kT, posT, sE, idxb,
                                                       w1i2, w2i2, cw2i2, fb2, sF);
  gemm_kern<<<gg, 256, 0, stream>>>(sF, 128, 128, warena + 147456, barena + 896, v0, sG, 0);
  out_kern<<<trg, 256, 0, stream>>>(sG, d_out, flags, 2);
}

// Round 9
// 511.617 us; speedup vs baseline: 1.1694x; 1.0645x over previous
//
#include <hip/hip_runtime.h>
#include <hip/hip_bf16.h>

typedef __hip_bfloat16 bf16;
typedef unsigned long long ull;

#define BB 4
#define NN 2048
#define CCH 128
#define DDM 128
#define KNB 16
#define HHD 64
#define AAD 512
#define PP (BB*NN)

typedef __attribute__((ext_vector_type(8))) short short8;
typedef __attribute__((ext_vector_type(16))) float f32x16;

__device__ __forceinline__ float b2f(bf16 x) { return __bfloat162float(x); }
__device__ __forceinline__ bf16 f2b(float x) { return __float2bfloat16(x); }

__device__ __forceinline__ float ldany(const void* p, size_t i, int f32) {
  return f32 ? ((const float*)p)[i] : __bfloat162float(((const bf16*)p)[i]);
}

__device__ __forceinline__ long pack4(float a, float b, float c, float d) {
  union { bf16 h[4]; long l; } u;
  u.h[0] = f2b(a); u.h[1] = f2b(b); u.h[2] = f2b(c); u.h[3] = f2b(d);
  return u.l;
}
__device__ __forceinline__ void unpack4(long l, float* o) {
  union { bf16 h[4]; long l; } u; u.l = l;
  o[0] = b2f(u.h[0]); o[1] = b2f(u.h[1]); o[2] = b2f(u.h[2]); o[3] = b2f(u.h[3]);
}

__device__ __forceinline__ short8 ldfrag(const bf16* base, int row, int stride, int k0, int hl) {
  const bf16* p = base + (size_t)row * stride + k0 + (hl << 3);
  union { short8 v; long l[2]; } u;
  u.l[0] = *(const long*)p;
  u.l[1] = *(const long*)(p + 4);
  return u.v;
}

__device__ __forceinline__ f32x16 MFMA(short8 a, short8 b, f32x16 c) {
  return __builtin_amdgcn_mfma_f32_32x32x16_bf16(a, b, c, 0, 0, 0);
}

struct PtrArr { const void* p[36]; int n[36]; };
struct CvtTab { int src[16]; int off[16]; int n[16]; int isb[16]; };
struct G4 { const bf16* X[4]; int K[4]; int woff[4]; int boff[4]; bf16* out[4]; int relu[4]; };

// ---------- dtype sniffer ----------
__global__ __launch_bounds__(256) void sniff_kern(PtrArr pa, int* __restrict__ flags) {
  int t = blockIdx.x;
  const bf16* x = (const bf16*)pa.p[t];
  int n = pa.n[t]; if (n > 4096) n = 4096;
  __shared__ int cnt;
  if (threadIdx.x == 0) cnt = 0;
  __syncthreads();
  int c = 0;
  for (int i = threadIdx.x; i < n; i += 256) {
    float v = fabsf(__bfloat162float(x[i]));
    if (v == 0.f || (v >= 1e-6f && v <= 1024.f)) c++;
  }
  atomicAdd(&cnt, c);
  __syncthreads();
  if (threadIdx.x == 0) flags[t] = (cnt >= (n * 7) / 8) ? 0 : 1;
}

// ---------- convert GEMM weights/biases into bf16 arena + fp32 bias arena ----------
__global__ __launch_bounds__(256) void wcvt_kern(PtrArr pa, CvtTab tab,
                                                 const int* __restrict__ flags,
                                                 bf16* __restrict__ warena,
                                                 float* __restrict__ barena) {
  int e = blockIdx.y;
  int i = blockIdx.x * 256 + threadIdx.x;
  if (i >= tab.n[e]) return;
  float v = ldany(pa.p[tab.src[e]], i, flags[tab.src[e]]);
  if (tab.isb[e]) barena[tab.off[e] + i] = v;
  else warena[tab.off[e] + i] = f2b(v);
}

// ---------- weight-image prep for BOTH attn blocks (y = set) ----------
__global__ __launch_bounds__(256) void prep2_kern(PtrArr pa,
                                                  const int* __restrict__ flags,
                                                  bf16* __restrict__ w1img0, bf16* __restrict__ w2img0,
                                                  bf16* __restrict__ cw2img0, float* __restrict__ fb0,
                                                  bf16* __restrict__ w1img1, bf16* __restrict__ w2img1,
                                                  bf16* __restrict__ cw2img1, float* __restrict__ fb1) {
  int set = blockIdx.y;
  int cIdx = set ? 20 : 16, aIdx = set ? 28 : 24, dd = set ? 2 : 3;
  bf16* w1img = set ? w1img1 : w1img0;
  bf16* w2img = set ? w2img1 : w2img0;
  bf16* cw2img = set ? cw2img1 : cw2img0;
  float* fb = set ? fb1 : fb0;
  const void* cw1 = pa.p[cIdx];     const void* cb1 = pa.p[cIdx + 1];
  const void* cw2 = pa.p[cIdx + 2]; const void* cb2 = pa.p[cIdx + 3];
  const void* aw1 = pa.p[aIdx];     const void* ab1 = pa.p[aIdx + 1];
  const void* aw2 = pa.p[aIdx + 2]; const void* ab2 = pa.p[aIdx + 3];
  int i = blockIdx.x * 256 + threadIdx.x;
  const int fcw1 = flags[cIdx], fcb1 = flags[cIdx + 1];
  const int fcw2 = flags[cIdx + 2], fcb2 = flags[cIdx + 3];
  const int faw1 = flags[aIdx], fab1 = flags[aIdx + 1];
  const int faw2 = flags[aIdx + 2], fab2 = flags[aIdx + 3];
  float* ab1f = fb;          // 512
  float* ab2f = fb + 512;    // 128
  float* cb1f = fb + 640;    // 64
  float* cb2f = fb + 704;    // 128
  float* cw1f = fb + 832;    // 192
  if (i < 65536) {                       // w1img: [h_glob 512][132]
    int hg = i >> 7, c = i & 127;
    w1img[(size_t)hg * 132 + c] = f2b(ldany(aw1, i, faw1));
  } else if (i < 131072) {               // w2img: [ac*128+o][132] col=h_local
    int j = i - 65536;
    int o = j >> 9, hh = j & 511;
    int ac = hh >> 7, hloc = hh & 127;
    w2img[(size_t)(ac * 128 + o) * 132 + hloc] = f2b(ldany(aw2, j, faw2));
  } else if (i < 139264) {               // cw2img: [o 128][68]
    int j = i - 131072;
    int o = j >> 6, h = j & 63;
    cw2img[o * 68 + h] = f2b(ldany(cw2, j, fcw2));
  } else if (i < 139776) {
    int j = i - 139264; ab1f[j] = ldany(ab1, j, fab1);
  } else if (i < 139904) {
    int j = i - 139776; ab2f[j] = ldany(ab2, j, fab2);
  } else if (i < 139968) {
    int j = i - 139904; cb1f[j] = ldany(cb1, j, fcb1);
  } else if (i < 140096) {
    int j = i - 139968; cb2f[j] = ldany(cb2, j, fcb2);
  } else if (i < 140288) {
    int j = i - 140096;
    int h = j / 3, c = j % 3;
    cw1f[j] = (c < dd) ? ldany(cw1, h * dd + c, fcw1) : 0.f;
  }
}

// ---------- fused transpose: key+query (B,128,N) raw -> catT (P,256) bf16 ----------
__global__ __launch_bounds__(256) void tr_in2_kern(const void* __restrict__ keyp,
                                                   const void* __restrict__ qryp,
                                                   const int* __restrict__ flags,
                                                   bf16* __restrict__ dst) {
  __shared__ float tile[64][65];
  int z = blockIdx.z, b = z & 3, half = z >> 2;
  const void* src = half ? qryp : keyp;
  const int f32 = flags[2 + half];
  int n0 = blockIdx.x * 64, c0 = blockIdx.y * 64;
  int tx = threadIdx.x & 63, ty = threadIdx.x >> 6;
  for (int r = ty; r < 64; r += 4)
    tile[r][tx] = ldany(src, (size_t)(b * 128 + c0 + r) * NN + n0 + tx, f32);
  __syncthreads();
  for (int r = ty; r < 64; r += 4)
    dst[(size_t)(b * NN + n0 + r) * 256 + half * 128 + c0 + tx] = __float2bfloat16(tile[tx][r]);
}

// ---------- fused coords: xyz+pos raw -> (P,4) fp32 each ----------
__global__ __launch_bounds__(256) void tr_coords2_kern(const void* __restrict__ xyzp,
                                                       const void* __restrict__ posp,
                                                       const int* __restrict__ flags,
                                                       float* __restrict__ xyzT,
                                                       float* __restrict__ posT) {
  int which = blockIdx.y;
  const void* src = which ? posp : xyzp;
  float* dst = which ? posT : xyzT;
  int dd = which ? 2 : 3;
  const int f32 = flags[which];
  int i = blockIdx.x * 256 + threadIdx.x;
  if (i >= PP * 4) return;
  int p = i >> 2, j = i & 3;
  int b = p >> 11, n = p & (NN - 1);
  dst[i] = (j < dd) ? ldany(src, (size_t)(b * dd + j) * NN + n, f32) : 0.f;
}

// ---------- fused 4-op MFMA GEMM over catT (64 tokens x 128 outs, op=blockIdx.y) ----------
__global__ __launch_bounds__(256) void gemm4_kern(G4 g, const bf16* __restrict__ warena,
                                                  const float* __restrict__ barena) {
  __shared__ __attribute__((aligned(16))) bf16 XT[64 * 260];
  int op = blockIdx.y;
  const bf16* X = g.X[op];
  int K = g.K[op];
  const bf16* Wb = warena + g.woff[op];
  const float* bias = barena + g.boff[op];
  bf16* out = g.out[op];
  int relu = g.relu[op];
  int tid = threadIdx.x, lane = tid & 63, wv = tid >> 6;
  int hl = lane >> 5, cA = lane & 31;
  int p0 = blockIdx.x * 64;
  int SK = K + 4;
  int kc = K >> 3;
  for (int c = tid; c < 64 * kc; c += 256) {
    int r = c / kc, col = (c % kc) << 3;
    *(float4*)&XT[r * SK + col] = *(const float4*)&X[(size_t)(p0 + r) * 256 + col];
  }
  __syncthreads();
  int o0 = wv * 32;
  f32x16 acc[2];
#pragma unroll
  for (int r = 0; r < 16; ++r) {
    int o = o0 + (r & 3) + 8 * (r >> 2) + 4 * hl;
    float bv = bias[o];
    acc[0][r] = bv; acc[1][r] = bv;
  }
  for (int ks = 0; ks < (K >> 4); ++ks) {
    short8 af = ldfrag(Wb, o0 + cA, K, ks * 16, hl);
    short8 b0 = ldfrag(XT, cA, SK, ks * 16, hl);
    short8 b1 = ldfrag(XT, 32 + cA, SK, ks * 16, hl);
    acc[0] = MFMA(af, b0, acc[0]);
    acc[1] = MFMA(af, b1, acc[1]);
  }
#pragma unroll
  for (int t = 0; t < 2; ++t) {
    int m = p0 + t * 32 + cA;
#pragma unroll
    for (int q = 0; q < 4; ++q) {
      int ob = o0 + 8 * q + 4 * hl;
      float v[4] = {acc[t][4*q+0], acc[t][4*q+1], acc[t][4*q+2], acc[t][4*q+3]};
      if (relu) {
        v[0] = fmaxf(v[0], 0.f); v[1] = fmaxf(v[1], 0.f);
        v[2] = fmaxf(v[2], 0.f); v[3] = fmaxf(v[3], 0.f);
      }
      *(long*)(out + (size_t)m * 128 + ob) = pack4(v[0], v[1], v[2], v[3]);
    }
  }
}

// ---------- standalone MFMA GEMM: 32 tokens x 128 outs (K=128), grid PP/32 ----------
__global__ __launch_bounds__(256) void gemm32_kern(
    const bf16* __restrict__ X,
    const bf16* __restrict__ Wb, const float* __restrict__ bias,
    const bf16* __restrict__ add, bf16* __restrict__ out, int relu) {
  __shared__ __attribute__((aligned(16))) bf16 XT[32 * 132];
  int tid = threadIdx.x, lane = tid & 63, wv = tid >> 6;
  int hl = lane >> 5, cA = lane & 31;
  int p0 = blockIdx.x * 32;
  for (int c = tid; c < 32 * 16; c += 256) {
    int r = c >> 4, col = (c & 15) << 3;
    *(float4*)&XT[r * 132 + col] = *(const float4*)&X[(size_t)(p0 + r) * 128 + col];
  }
  __syncthreads();
  int o0 = wv * 32;
  f32x16 acc;
#pragma unroll
  for (int r = 0; r < 16; ++r) {
    int o = o0 + (r & 3) + 8 * (r >> 2) + 4 * hl;
    acc[r] = bias[o];
  }
#pragma unroll
  for (int ks = 0; ks < 8; ++ks) {
    short8 af = ldfrag(Wb, o0 + cA, 128, ks * 16, hl);
    short8 b0 = ldfrag(XT, cA, 132, ks * 16, hl);
    acc = MFMA(af, b0, acc);
  }
  int m = p0 + cA;
#pragma unroll
  for (int q = 0; q < 4; ++q) {
    int ob = o0 + 8 * q + 4 * hl;
    float v[4] = {acc[4*q+0], acc[4*q+1], acc[4*q+2], acc[4*q+3]};
    if (add) {
      float av[4];
      unpack4(*(const long*)(add + (size_t)m * 128 + ob), av);
      v[0] += av[0]; v[1] += av[1]; v[2] += av[2]; v[3] += av[3];
    }
    if (relu) {
      v[0] = fmaxf(v[0], 0.f); v[1] = fmaxf(v[1], 0.f);
      v[2] = fmaxf(v[2], 0.f); v[3] = fmaxf(v[3], 0.f);
    }
    *(long*)(out + (size_t)m * 128 + ob) = pack4(v[0], v[1], v[2], v[3]);
  }
}

// ---------- kNN: 8 points/block (8 waves), register top-16 + wave merge ----------
__global__ __launch_bounds__(512) void knn_kern(const float* __restrict__ coordsT,
                                                int* __restrict__ idxout) {
  __shared__ __attribute__((aligned(16))) float4 cds[NN];
  int tid = threadIdx.x, lane = tid & 63, wv = tid >> 6;
  int p0 = blockIdx.x * 8, b = p0 >> 11;
  for (int j = tid; j < NN; j += 512)
    cds[j] = *(const float4*)&coordsT[((size_t)(b << 11) + j) * 4];
  __syncthreads();
  int p = p0 + wv, n = p & (NN - 1);
  float4 cc = cds[n];
  float sqi = __fadd_rn(__fadd_rn(__fmul_rn(cc.x, cc.x), __fmul_rn(cc.y, cc.y)),
                        __fmul_rn(cc.z, cc.z));
  ull t[16];
#pragma unroll
  for (int i = 0; i < 16; ++i) t[i] = ~0ull;
  for (int s = 0; s < 32; ++s) {
    int j = (s << 6) | lane;
    float4 q = cds[j];
    float sqj = __fadd_rn(__fadd_rn(__fmul_rn(q.x, q.x), __fmul_rn(q.y, q.y)),
                          __fmul_rn(q.z, q.z));
    float dt  = __fadd_rn(__fadd_rn(__fmul_rn(cc.x, q.x), __fmul_rn(cc.y, q.y)),
                          __fmul_rn(cc.z, q.z));
    float d2 = __fsub_rn(__fadd_rn(sqi, sqj), __fmul_rn(2.f, dt));
    unsigned u = __float_as_uint(d2);
    u = (u & 0x80000000u) ? ~u : (u | 0x80000000u);
    ull key = ((ull)u << 32) | (unsigned)j;
    if (key < t[15]) {
      t[15] = key;
#pragma unroll
      for (int i = 15; i > 0; --i) {
        ull lo = t[i - 1] < t[i] ? t[i - 1] : t[i];
        ull hi = t[i - 1] < t[i] ? t[i] : t[i - 1];
        t[i - 1] = lo; t[i] = hi;
      }
    }
  }
  for (int r = 0; r < KNB; ++r) {
    ull h = t[0];
    ull m = h;
#pragma unroll
    for (int off = 1; off < 64; off <<= 1) {
      ull o = __shfl_xor(m, off);
      m = o < m ? o : m;
    }
    if (lane == 0) idxout[(size_t)p * KNB + r] = (int)(m & 0xffffffffu);
    if (h == m) {
#pragma unroll
      for (int i = 0; i < 15; ++i) t[i] = t[i + 1];
      t[15] = ~0ull;
    }
  }
}

// ---------- MFMA fused kNN attention (round-8 structure, unchanged) ----------
#define SMEM_BYTES 72192
__global__ __launch_bounds__(512, 4) void attn_mfma(
    const bf16* __restrict__ centerT, const bf16* __restrict__ gatherT,
    const float* __restrict__ coordsT, const bf16* __restrict__ vfeatT,
    const int* __restrict__ idx,
    const bf16* __restrict__ w1img, const bf16* __restrict__ w2img,
    const bf16* __restrict__ cw2img, const float* __restrict__ fb,
    bf16* __restrict__ aggT) {
  extern __shared__ char smem[];
  bf16* XS  = (bf16*)(smem);            // [128][132]
  bf16* HT  = (bf16*)(smem + 33792);    // [128][132]
  bf16* HC  = HT;                       // [128][68] aliases HT (dead before chunk 0)
  bf16* CFE = (bf16*)(smem + 67584);    // [8][128]
  bf16* VF  = (bf16*)(smem + 69632);    // [8][128]
  int*  NID = (int*)(smem + 71680);     // [128]
  const float* ab1f = fb;
  const float* ab2f = fb + 512;
  const float* cb1f = fb + 640;
  const float* cb2f = fb + 704;
  const float* cw1f = fb + 832;

  int tid = threadIdx.x, lane = tid & 63, wv = tid >> 6;
  int hl = lane >> 5, cA = lane & 31;
  int P0 = blockIdx.x * 8, b = P0 >> 11;

  if (tid < 128) NID[tid] = (b << 11) + idx[(size_t)(P0 + (tid >> 4)) * KNB + (tid & 15)];
  for (int i = tid; i < 1024; i += 512) {
    int g = i >> 7, d = i & 127;
    CFE[i] = centerT[(size_t)(P0 + g) * 128 + d];
    VF[i]  = vfeatT[(size_t)(P0 + g) * 128 + d];
  }
  __syncthreads();

  // phase 1: coord hidden HC + XS base (= cfe - gathered)
  {
    int m = tid >> 2, sub = tid & 3;
    float4 ccd = *(const float4*)&coordsT[(size_t)(P0 + (m >> 4)) * 4];
    float4 nbd = *(const float4*)&coordsT[(size_t)NID[m] * 4];
    float r0 = ccd.x - nbd.x, r1 = ccd.y - nbd.y, r2 = ccd.z - nbd.z;
    int h0 = sub * 16;
    for (int hh = h0; hh < h0 + 16; hh += 4) {
      float a0 = fmaxf(cb1f[hh+0] + cw1f[(hh+0)*3]*r0 + cw1f[(hh+0)*3+1]*r1 + cw1f[(hh+0)*3+2]*r2, 0.f);
      float a1 = fmaxf(cb1f[hh+1] + cw1f[(hh+1)*3]*r0 + cw1f[(hh+1)*3+1]*r1 + cw1f[(hh+1)*3+2]*r2, 0.f);
      float a2 = fmaxf(cb1f[hh+2] + cw1f[(hh+2)*3]*r0 + cw1f[(hh+2)*3+1]*r1 + cw1f[(hh+2)*3+2]*r2, 0.f);
      float a3 = fmaxf(cb1f[hh+3] + cw1f[(hh+3)*3]*r0 + cw1f[(hh+3)*3+1]*r1 + cw1f[(hh+3)*3+2]*r2, 0.f);
      *(long*)&HC[m * 68 + hh] = pack4(a0, a1, a2, a3);
    }
    const bf16* grow = gatherT + (size_t)NID[m] * 128 + sub * 32;
    const bf16* crow = CFE + ((m >> 4) << 7) + sub * 32;
    for (int j = 0; j < 32; j += 4) {
      float gv[4], cv[4];
      unpack4(*(const long*)(grow + j), gv);
      unpack4(*(const long*)(crow + j), cv);
      *(long*)&XS[m * 132 + sub * 32 + j] =
          pack4(cv[0] - gv[0], cv[1] - gv[1], cv[2] - gv[2], cv[3] - gv[3]);
    }
  }
  __syncthreads();

  int r0s = (wv & 3) * 32;     // output-row strip (o / h)
  int mt0 = (wv >> 2) * 64;    // token strip (2 tiles of 32)

  // preload chunk-0 W1 fragments (in flight across the emb GEMM)
  short8 pf[8];
#pragma unroll
  for (int ks = 0; ks < 8; ++ks)
    pf[ks] = ldfrag(w1img, r0s + cA, 132, ks * 16, hl);

  // phase 2: emb GEMM (C_e[o][m] = cw2 @ HC + cb2), RMW into XS
  {
    f32x16 eacc[2];
#pragma unroll
    for (int r = 0; r < 16; ++r) {
      int o = r0s + (r & 3) + 8 * (r >> 2) + 4 * hl;
      float bv = cb2f[o];
      eacc[0][r] = bv; eacc[1][r] = bv;
    }
    for (int k0 = 0; k0 < 64; k0 += 16) {
      short8 af = ldfrag(cw2img, r0s + cA, 68, k0, hl);   // global, L2-hot
      short8 b0 = ldfrag(HC, mt0 + cA, 68, k0, hl);
      short8 b1 = ldfrag(HC, mt0 + 32 + cA, 68, k0, hl);
      eacc[0] = MFMA(af, b0, eacc[0]);
      eacc[1] = MFMA(af, b1, eacc[1]);
    }
#pragma unroll
    for (int t = 0; t < 2; ++t) {
      int m = mt0 + t * 32 + cA;
#pragma unroll
      for (int q = 0; q < 4; ++q) {
        int ob = r0s + 8 * q + 4 * hl;
        bf16* px = &XS[m * 132 + ob];
        float xv[4];
        unpack4(*(long*)px, xv);
        *(long*)px = pack4(xv[0] + eacc[t][4*q+0], xv[1] + eacc[t][4*q+1],
                           xv[2] + eacc[t][4*q+2], xv[3] + eacc[t][4*q+3]);
      }
    }
  }
  __syncthreads();

  // logits accumulator (bias-init)
  f32x16 acc2[2];
#pragma unroll
  for (int r = 0; r < 16; ++r) {
    int o = r0s + (r & 3) + 8 * (r >> 2) + 4 * hl;
    float bv = ab2f[o];
    acc2[0][r] = bv; acc2[1][r] = bv;
  }

  // chunk loop: 4 x 128 hidden; pf[] rotates W1(chunk ac) -> W2(ac) -> W1(ac+1)
  for (int ac = 0; ac < 4; ++ac) {
    const bf16* w2c = w2img + (size_t)ac * 16896;
    const bf16* w1n = w1img + (size_t)((ac + 1) & 3) * 16896;
    f32x16 acc1[2];
#pragma unroll
    for (int r = 0; r < 16; ++r) {
      int h = r0s + (r & 3) + 8 * (r >> 2) + 4 * hl;
      float bv = ab1f[ac * 128 + h];
      acc1[0][r] = bv; acc1[1][r] = bv;
    }
#pragma unroll
    for (int ks = 0; ks < 8; ++ks) {
      short8 af = pf[ks];
      short8 b0 = ldfrag(XS, mt0 + cA, 132, ks * 16, hl);
      short8 b1 = ldfrag(XS, mt0 + 32 + cA, 132, ks * 16, hl);
      pf[ks] = ldfrag(w2c, r0s + cA, 132, ks * 16, hl);
      acc1[0] = MFMA(af, b0, acc1[0]);
      acc1[1] = MFMA(af, b1, acc1[1]);
    }
    __syncthreads();
#pragma unroll
    for (int t = 0; t < 2; ++t) {
      int m = mt0 + t * 32 + cA;
#pragma unroll
      for (int q = 0; q < 4; ++q) {
        int hb = r0s + 8 * q + 4 * hl;
        *(long*)&HT[m * 132 + hb] =
            pack4(fmaxf(acc1[t][4*q+0], 0.f), fmaxf(acc1[t][4*q+1], 0.f),
                  fmaxf(acc1[t][4*q+2], 0.f), fmaxf(acc1[t][4*q+3], 0.f));
      }
    }
    __syncthreads();
#pragma unroll
    for (int ks = 0; ks < 8; ++ks) {
      short8 af = pf[ks];
      short8 b0 = ldfrag(HT, mt0 + cA, 132, ks * 16, hl);
      short8 b1 = ldfrag(HT, mt0 + 32 + cA, 132, ks * 16, hl);
      pf[ks] = ldfrag(w1n, r0s + cA, 132, ks * 16, hl);
      acc2[0] = MFMA(af, b0, acc2[0]);
      acc2[1] = MFMA(af, b1, acc2[1]);
    }
  }

  // softmax-one over kk (16-lane groups) + aggregation
#pragma unroll
  for (int t = 0; t < 2; ++t) {
    int m = mt0 + t * 32 + cA;
    int g = m >> 4;
    float a[16];
#pragma unroll
    for (int r = 0; r < 16; ++r) {
      float x = acc2[t][r];
      float mx = x;
      mx = fmaxf(mx, __shfl_xor(mx, 1, 16));
      mx = fmaxf(mx, __shfl_xor(mx, 2, 16));
      mx = fmaxf(mx, __shfl_xor(mx, 4, 16));
      mx = fmaxf(mx, __shfl_xor(mx, 8, 16));
      float e = __expf(x - mx);
      float s = e;
      s += __shfl_xor(s, 1, 16);
      s += __shfl_xor(s, 2, 16);
      s += __shfl_xor(s, 4, 16);
      s += __shfl_xor(s, 8, 16);
      a[r] = e / (1.f + s);
    }
#pragma unroll
    for (int q = 0; q < 4; ++q) {
      int ob = r0s + 8 * q + 4 * hl;
      float xv[4], gv[4], vv[4], cv[4];
      unpack4(*(long*)&XS[m * 132 + ob], xv);
      unpack4(*(const long*)(gatherT + (size_t)NID[m] * 128 + ob), gv);
      unpack4(*(long*)&VF[(g << 7) + ob], vv);
      unpack4(*(long*)&CFE[(g << 7) + ob], cv);
      float p0 = a[4*q+0] * (vv[0] - cv[0] + xv[0] + gv[0]);
      float p1 = a[4*q+1] * (vv[1] - cv[1] + xv[1] + gv[1]);
      float p2 = a[4*q+2] * (vv[2] - cv[2] + xv[2] + gv[2]);
      float p3 = a[4*q+3] * (vv[3] - cv[3] + xv[3] + gv[3]);
#pragma unroll
      for (int s = 1; s < 16; s <<= 1) {
        p0 += __shfl_xor(p0, s, 16);
        p1 += __shfl_xor(p1, s, 16);
        p2 += __shfl_xor(p2, s, 16);
        p3 += __shfl_xor(p3, s, 16);
      }
      if ((lane & 15) == 0)
        *(long*)(aggT + (size_t)(P0 + g) * 128 + ob) = pack4(p0, p1, p2, p3);
    }
  }
}

// ---------- token-major bf16 (P,128) -> (B,128,N) output ----------
__global__ __launch_bounds__(256) void out_kern(const bf16* __restrict__ yT,
                                                void* __restrict__ outp,
                                                const int* __restrict__ flags, int ofIdx) {
  __shared__ float tile[64][65];
  const int f32 = flags[ofIdx];
  int b = blockIdx.z, n0 = blockIdx.x * 64, c0 = blockIdx.y * 64;
  int tx = threadIdx.x & 63, ty = threadIdx.x >> 6;
  for (int r = ty; r < 64; r += 4)
    tile[r][tx] = b2f(yT[(size_t)(b * NN + n0 + r) * 128 + c0 + tx]);
  __syncthreads();
  for (int r = ty; r < 64; r += 4) {
    size_t oi = (size_t)(b * CCH + c0 + r) * NN + n0 + tx;
    float v = tile[tx][r];
    if (f32) ((float*)outp)[oi] = v;
    else ((bf16*)outp)[oi] = __float2bfloat16(v);
  }
}

extern "C" void kernel_launch(void* const* d_in, const int* in_sizes, int n_in,
                              void* d_out, int out_size, void* d_ws, size_t ws_size,
                              hipStream_t stream) {
  // workspace layout
  int* flags = (int*)d_ws;
  bf16* catT = (bf16*)((float*)d_ws + 64);        // P x 256
  bf16* v0   = catT + (size_t)PP * 256;
  bf16* kT   = v0 + (size_t)PP * 128;
  bf16* qT   = kT + (size_t)PP * 128;
  bf16* sE   = qT + (size_t)PP * 128;             // vT, then value2
  bf16* sF   = sE + (size_t)PP * 128;             // tmp, agg1, agg2
  bf16* sG   = sF + (size_t)PP * 128;             // shortb, val1, yT
  float* xyzT = (float*)(sG + (size_t)PP * 128);  // P x 4
  float* posT = xyzT + (size_t)PP * 4;
  int* idxb = (int*)(posT + (size_t)PP * 4);      // P x 16
  bf16* w1i1 = (bf16*)(idxb + (size_t)PP * KNB);  // 4*128*132
  bf16* w2i1 = w1i1 + 67584;
  bf16* cw2i1 = w2i1 + 67584;                     // 128*68
  bf16* w1i2 = cw2i1 + 8704;
  bf16* w2i2 = w1i2 + 67584;
  bf16* cw2i2 = w2i2 + 67584;
  float* fb1 = (float*)(cw2i2 + 8704);            // 1024 floats
  float* fb2 = fb1 + 1024;
  bf16* warena = (bf16*)(fb2 + 1024);             // 163840 bf16
  float* barena = (float*)(warena + 163840);      // 1024 fp32

  PtrArr pa;
  for (int i = 0; i < 36; ++i) { pa.p[i] = d_in[i]; pa.n[i] = in_sizes[i]; }
  sniff_kern<<<dim3(36), 256, 0, stream>>>(pa, flags);

  CvtTab tab;
  int wsrc[8] = {4, 8, 6, 10, 12, 14, 32, 34};
  int woff[8] = {0, 32768, 65536, 81920, 98304, 114688, 131072, 147456};
  int wn[8]   = {32768, 32768, 16384, 16384, 16384, 16384, 16384, 16384};
  int bsrc[8] = {5, 9, 7, 11, 13, 15, 33, 35};
  for (int e = 0; e < 8; ++e) {
    tab.src[e] = wsrc[e]; tab.off[e] = woff[e]; tab.n[e] = wn[e]; tab.isb[e] = 0;
    tab.src[8 + e] = bsrc[e]; tab.off[8 + e] = e * 128; tab.n[8 + e] = 128; tab.isb[8 + e] = 1;
  }
  wcvt_kern<<<dim3(128, 16), 256, 0, stream>>>(pa, tab, flags, warena, barena);
  prep2_kern<<<dim3(548, 2), 256, 0, stream>>>(pa, flags,
                                               w1i1, w2i1, cw2i1, fb1,
                                               w1i2, w2i2, cw2i2, fb2);

  tr_in2_kern<<<dim3(32, 2, 8), 256, 0, stream>>>(d_in[2], d_in[3], flags, catT);
  tr_coords2_kern<<<dim3(128, 2), 256, 0, stream>>>(d_in[0], d_in[1], flags, xyzT, posT);

  // fused frontend: mv_w1 -> sF(relu), mv_ws -> sG, wk -> kT, wq -> qT
  G4 g4;
  g4.X[0] = catT;       g4.K[0] = 256; g4.woff[0] = 0;      g4.boff[0] = 0;   g4.out[0] = sF; g4.relu[0] = 1;
  g4.X[1] = catT;       g4.K[1] = 256; g4.woff[1] = 32768;  g4.boff[1] = 128; g4.out[1] = sG; g4.relu[1] = 0;
  g4.X[2] = catT;       g4.K[2] = 128; g4.woff[2] = 81920;  g4.boff[2] = 384; g4.out[2] = kT; g4.relu[2] = 0;
  g4.X[3] = catT + 128; g4.K[3] = 128; g4.woff[3] = 98304;  g4.boff[3] = 512; g4.out[3] = qT; g4.relu[3] = 0;
  gemm4_kern<<<dim3(PP / 64, 4), 256, 0, stream>>>(g4, warena, barena);

  dim3 g32(PP / 32);
  gemm32_kern<<<g32, 256, 0, stream>>>(sF, warena + 65536,  barena + 256, sG,      v0, 0);  // mv_w2 + shortcut
  gemm32_kern<<<g32, 256, 0, stream>>>(v0, warena + 114688, barena + 640, nullptr, sE, 0);  // wv

  hipFuncSetAttribute((const void*)attn_mfma, hipFuncAttributeMaxDynamicSharedMemorySize, SMEM_BYTES);

  // block 1 (xyz): center=k, gathered=q, vfeat=v
  knn_kern<<<dim3(PP / 8), 512, 0, stream>>>(xyzT, idxb);
  attn_mfma<<<dim3(PP / 8), 512, SMEM_BYTES, stream>>>(kT, qT, xyzT, sE, idxb,
                                                       w1i1, w2i1, cw2i1, fb1, sF);
  gemm32_kern<<<g32, 256, 0, stream>>>(sF, warena + 131072, barena + 768, v0,      sG, 0);  // wkq + identity
  gemm32_kern<<<g32, 256, 0, stream>>>(sG, warena + 114688, barena + 640, nullptr, sE, 0);  // wv (value2)
  // block 2 (pos): center=q, gathered=k, vfeat=value2
  knn_kern<<<dim3(PP / 8), 512, 0, stream>>>(posT, idxb);
  attn_mfma<<<dim3(PP / 8), 512, SMEM_BYTES, stream>>>(qT, kT, posT, sE, idxb,
                                                       w1i2, w2i2, cw2i2, fb2, sF);
  gemm32_kern<<<g32, 256, 0, stream>>>(sF, warena + 147456, barena + 896, v0, sG, 0);       // wend + identity
  out_kern<<<dim3(32, 2, 4), 256, 0, stream>>>(sG, d_out, flags, 2);
}

// Round 10
// 470.098 us; speedup vs baseline: 1.2727x; 1.0883x over previous
//
#include <hip/hip_runtime.h>
#include <hip/hip_bf16.h>

typedef __hip_bfloat16 bf16;
typedef unsigned long long ull;

#define BB 4
#define NN 2048
#define CCH 128
#define DDM 128
#define KNB 16
#define HHD 64
#define AAD 512
#define PP (BB*NN)

typedef __attribute__((ext_vector_type(8))) short short8;
typedef __attribute__((ext_vector_type(16))) float f32x16;

__device__ __forceinline__ float b2f(bf16 x) { return __bfloat162float(x); }
__device__ __forceinline__ bf16 f2b(float x) { return __float2bfloat16(x); }

__device__ __forceinline__ float ldany(const void* p, size_t i, int f32) {
  return f32 ? ((const float*)p)[i] : __bfloat162float(((const bf16*)p)[i]);
}

__device__ __forceinline__ long pack4(float a, float b, float c, float d) {
  union { bf16 h[4]; long l; } u;
  u.h[0] = f2b(a); u.h[1] = f2b(b); u.h[2] = f2b(c); u.h[3] = f2b(d);
  return u.l;
}
__device__ __forceinline__ void unpack4(long l, float* o) {
  union { bf16 h[4]; long l; } u; u.l = l;
  o[0] = b2f(u.h[0]); o[1] = b2f(u.h[1]); o[2] = b2f(u.h[2]); o[3] = b2f(u.h[3]);
}

__device__ __forceinline__ short8 ldfrag(const bf16* base, int row, int stride, int k0, int hl) {
  const bf16* p = base + (size_t)row * stride + k0 + (hl << 3);
  union { short8 v; long l[2]; } u;
  u.l[0] = *(const long*)p;
  u.l[1] = *(const long*)(p + 4);
  return u.v;
}

__device__ __forceinline__ f32x16 MFMA(short8 a, short8 b, f32x16 c) {
  return __builtin_amdgcn_mfma_f32_32x32x16_bf16(a, b, c, 0, 0, 0);
}

struct PtrArr { const void* p[36]; int n[36]; };
struct CvtTab { int src[16]; int off[16]; int n[16]; int isb[16]; };
struct G4 { const bf16* X[4]; int K[4]; int woff[4]; int boff[4]; bf16* out[4]; int relu[4]; };

// ---------- dtype sniffer ----------
__global__ __launch_bounds__(256) void sniff_kern(PtrArr pa, int* __restrict__ flags) {
  int t = blockIdx.x;
  const bf16* x = (const bf16*)pa.p[t];
  int n = pa.n[t]; if (n > 4096) n = 4096;
  __shared__ int cnt;
  if (threadIdx.x == 0) cnt = 0;
  __syncthreads();
  int c = 0;
  for (int i = threadIdx.x; i < n; i += 256) {
    float v = fabsf(__bfloat162float(x[i]));
    if (v == 0.f || (v >= 1e-6f && v <= 1024.f)) c++;
  }
  atomicAdd(&cnt, c);
  __syncthreads();
  if (threadIdx.x == 0) flags[t] = (cnt >= (n * 7) / 8) ? 0 : 1;
}

// ---------- fused convert: y<2 -> attn weight images (set=y); y>=2 -> GEMM arena entry ----------
__global__ __launch_bounds__(256) void cvtprep_kern(PtrArr pa, CvtTab tab,
                                                    const int* __restrict__ flags,
                                                    bf16* __restrict__ warena, float* __restrict__ barena,
                                                    bf16* __restrict__ w1img0, bf16* __restrict__ w2img0,
                                                    bf16* __restrict__ cw2img0, float* __restrict__ fb0,
                                                    bf16* __restrict__ w1img1, bf16* __restrict__ w2img1,
                                                    bf16* __restrict__ cw2img1, float* __restrict__ fb1) {
  int y = blockIdx.y;
  if (y >= 2) {                       // GEMM weight/bias arena
    int e = y - 2;
    int i = blockIdx.x * 256 + threadIdx.x;
    if (i >= tab.n[e]) return;
    float v = ldany(pa.p[tab.src[e]], i, flags[tab.src[e]]);
    if (tab.isb[e]) barena[tab.off[e] + i] = v;
    else warena[tab.off[e] + i] = f2b(v);
    return;
  }
  int set = y;
  int cIdx = set ? 20 : 16, aIdx = set ? 28 : 24, dd = set ? 2 : 3;
  bf16* w1img = set ? w1img1 : w1img0;
  bf16* w2img = set ? w2img1 : w2img0;
  bf16* cw2img = set ? cw2img1 : cw2img0;
  float* fb = set ? fb1 : fb0;
  const void* cw1 = pa.p[cIdx];     const void* cb1 = pa.p[cIdx + 1];
  const void* cw2 = pa.p[cIdx + 2]; const void* cb2 = pa.p[cIdx + 3];
  const void* aw1 = pa.p[aIdx];     const void* ab1 = pa.p[aIdx + 1];
  const void* aw2 = pa.p[aIdx + 2]; const void* ab2 = pa.p[aIdx + 3];
  int i = blockIdx.x * 256 + threadIdx.x;
  const int fcw1 = flags[cIdx], fcb1 = flags[cIdx + 1];
  const int fcw2 = flags[cIdx + 2], fcb2 = flags[cIdx + 3];
  const int faw1 = flags[aIdx], fab1 = flags[aIdx + 1];
  const int faw2 = flags[aIdx + 2], fab2 = flags[aIdx + 3];
  float* ab1f = fb;          // 512
  float* ab2f = fb + 512;    // 128
  float* cb1f = fb + 640;    // 64
  float* cb2f = fb + 704;    // 128
  float* cw1f = fb + 832;    // 192
  if (i < 65536) {                       // w1img: [h_glob 512][132]
    int hg = i >> 7, c = i & 127;
    w1img[(size_t)hg * 132 + c] = f2b(ldany(aw1, i, faw1));
  } else if (i < 131072) {               // w2img: [ac*128+o][132] col=h_local
    int j = i - 65536;
    int o = j >> 9, hh = j & 511;
    int ac = hh >> 7, hloc = hh & 127;
    w2img[(size_t)(ac * 128 + o) * 132 + hloc] = f2b(ldany(aw2, j, faw2));
  } else if (i < 139264) {               // cw2img: [o 128][68]
    int j = i - 131072;
    int o = j >> 6, h = j & 63;
    cw2img[o * 68 + h] = f2b(ldany(cw2, j, fcw2));
  } else if (i < 139776) {
    int j = i - 139264; ab1f[j] = ldany(ab1, j, fab1);
  } else if (i < 139904) {
    int j = i - 139776; ab2f[j] = ldany(ab2, j, fab2);
  } else if (i < 139968) {
    int j = i - 139904; cb1f[j] = ldany(cb1, j, fcb1);
  } else if (i < 140096) {
    int j = i - 139968; cb2f[j] = ldany(cb2, j, fcb2);
  } else if (i < 140288) {
    int j = i - 140096;
    int h = j / 3, c = j % 3;
    cw1f[j] = (c < dd) ? ldany(cw1, h * dd + c, fcw1) : 0.f;
  }
}

// ---------- fused transpose: x<512 key/query -> catT; x>=512 coords -> xyzT/posT ----------
__global__ __launch_bounds__(256) void trall_kern(const void* __restrict__ keyp,
                                                  const void* __restrict__ qryp,
                                                  const void* __restrict__ xyzp,
                                                  const void* __restrict__ posp,
                                                  const int* __restrict__ flags,
                                                  bf16* __restrict__ catT,
                                                  float* __restrict__ xyzT,
                                                  float* __restrict__ posT) {
  int bx = blockIdx.x;
  if (bx < 512) {
    __shared__ float tile[64][65];
    int xx = bx & 31, yy = (bx >> 5) & 1, zz = bx >> 6;
    int b = zz & 3, half = zz >> 2;
    const void* src = half ? qryp : keyp;
    const int f32 = flags[2 + half];
    int n0 = xx * 64, c0 = yy * 64;
    int tx = threadIdx.x & 63, ty = threadIdx.x >> 6;
    for (int r = ty; r < 64; r += 4)
      tile[r][tx] = ldany(src, (size_t)(b * 128 + c0 + r) * NN + n0 + tx, f32);
    __syncthreads();
    for (int r = ty; r < 64; r += 4)
      catT[(size_t)(b * NN + n0 + r) * 256 + half * 128 + c0 + tx] = __float2bfloat16(tile[tx][r]);
    return;
  }
  int cb = bx - 512;                 // 0..255
  int which = cb >> 7;               // 0: xyz, 1: pos
  const void* src = which ? posp : xyzp;
  float* dst = which ? posT : xyzT;
  int dd = which ? 2 : 3;
  const int f32 = flags[which];
  int i = (cb & 127) * 256 * 2 + threadIdx.x;   // two strides of 256 per block
  for (int rep = 0; rep < 2; ++rep, i += 256) {
    if (i < PP * 4) {
      int p = i >> 2, j = i & 3;
      int b = p >> 11, n = p & (NN - 1);
      dst[i] = (j < dd) ? ldany(src, (size_t)(b * dd + j) * NN + n, f32) : 0.f;
    }
  }
}

// ---------- fused 4-op MFMA GEMM over catT (64 tokens x 128 outs, op=blockIdx.y) ----------
__global__ __launch_bounds__(256) void gemm4_kern(G4 g, const bf16* __restrict__ warena,
                                                  const float* __restrict__ barena) {
  __shared__ __attribute__((aligned(16))) bf16 XT[64 * 260];
  int op = blockIdx.y;
  const bf16* X = g.X[op];
  int K = g.K[op];
  const bf16* Wb = warena + g.woff[op];
  const float* bias = barena + g.boff[op];
  bf16* out = g.out[op];
  int relu = g.relu[op];
  int tid = threadIdx.x, lane = tid & 63, wv = tid >> 6;
  int hl = lane >> 5, cA = lane & 31;
  int p0 = blockIdx.x * 64;
  int SK = K + 4;
  int kc = K >> 3;
  for (int c = tid; c < 64 * kc; c += 256) {
    int r = c / kc, col = (c % kc) << 3;
    *(float4*)&XT[r * SK + col] = *(const float4*)&X[(size_t)(p0 + r) * 256 + col];
  }
  __syncthreads();
  int o0 = wv * 32;
  f32x16 acc[2];
#pragma unroll
  for (int r = 0; r < 16; ++r) {
    int o = o0 + (r & 3) + 8 * (r >> 2) + 4 * hl;
    float bv = bias[o];
    acc[0][r] = bv; acc[1][r] = bv;
  }
  for (int ks = 0; ks < (K >> 4); ++ks) {
    short8 af = ldfrag(Wb, o0 + cA, K, ks * 16, hl);
    short8 b0 = ldfrag(XT, cA, SK, ks * 16, hl);
    short8 b1 = ldfrag(XT, 32 + cA, SK, ks * 16, hl);
    acc[0] = MFMA(af, b0, acc[0]);
    acc[1] = MFMA(af, b1, acc[1]);
  }
#pragma unroll
  for (int t = 0; t < 2; ++t) {
    int m = p0 + t * 32 + cA;
#pragma unroll
    for (int q = 0; q < 4; ++q) {
      int ob = o0 + 8 * q + 4 * hl;
      float v[4] = {acc[t][4*q+0], acc[t][4*q+1], acc[t][4*q+2], acc[t][4*q+3]};
      if (relu) {
        v[0] = fmaxf(v[0], 0.f); v[1] = fmaxf(v[1], 0.f);
        v[2] = fmaxf(v[2], 0.f); v[3] = fmaxf(v[3], 0.f);
      }
      *(long*)(out + (size_t)m * 128 + ob) = pack4(v[0], v[1], v[2], v[3]);
    }
  }
}

// ---------- standalone MFMA GEMM: 32 tokens x 128 outs (K=128) ----------
// outT != nullptr: write (B,128,N)-layout output (dtype per flags[2]) instead of token-major.
__global__ __launch_bounds__(256) void gemm32_kern(
    const bf16* __restrict__ X,
    const bf16* __restrict__ Wb, const float* __restrict__ bias,
    const bf16* __restrict__ add, bf16* __restrict__ out, int relu,
    void* __restrict__ outT, const int* __restrict__ flags) {
  __shared__ __attribute__((aligned(16))) bf16 XT[32 * 132];
  int tid = threadIdx.x, lane = tid & 63, wv = tid >> 6;
  int hl = lane >> 5, cA = lane & 31;
  int p0 = blockIdx.x * 32;
  for (int c = tid; c < 32 * 16; c += 256) {
    int r = c >> 4, col = (c & 15) << 3;
    *(float4*)&XT[r * 132 + col] = *(const float4*)&X[(size_t)(p0 + r) * 128 + col];
  }
  __syncthreads();
  int o0 = wv * 32;
  f32x16 acc;
#pragma unroll
  for (int r = 0; r < 16; ++r) {
    int o = o0 + (r & 3) + 8 * (r >> 2) + 4 * hl;
    acc[r] = bias[o];
  }
#pragma unroll
  for (int ks = 0; ks < 8; ++ks) {
    short8 af = ldfrag(Wb, o0 + cA, 128, ks * 16, hl);
    short8 b0 = ldfrag(XT, cA, 132, ks * 16, hl);
    acc = MFMA(af, b0, acc);
  }
  int m = p0 + cA;
  int f32o = outT ? flags[2] : 0;
  int b = m >> 11, n = m & (NN - 1);
#pragma unroll
  for (int q = 0; q < 4; ++q) {
    int ob = o0 + 8 * q + 4 * hl;
    float v[4] = {acc[4*q+0], acc[4*q+1], acc[4*q+2], acc[4*q+3]};
    if (add) {
      float av[4];
      unpack4(*(const long*)(add + (size_t)m * 128 + ob), av);
      v[0] += av[0]; v[1] += av[1]; v[2] += av[2]; v[3] += av[3];
    }
    if (relu) {
      v[0] = fmaxf(v[0], 0.f); v[1] = fmaxf(v[1], 0.f);
      v[2] = fmaxf(v[2], 0.f); v[3] = fmaxf(v[3], 0.f);
    }
    if (outT) {
#pragma unroll
      for (int i = 0; i < 4; ++i) {
        size_t oi = (size_t)(b * 128 + ob + i) * NN + n;
        if (f32o) ((float*)outT)[oi] = v[i];
        else ((bf16*)outT)[oi] = f2b(v[i]);
      }
    } else {
      *(long*)(out + (size_t)m * 128 + ob) = pack4(v[0], v[1], v[2], v[3]);
    }
  }
}

// ---------- kNN: 8 points/block (8 waves), register top-16 + wave merge ----------
__global__ __launch_bounds__(512) void knn_kern(const float* __restrict__ coordsT,
                                                int* __restrict__ idxout) {
  __shared__ __attribute__((aligned(16))) float4 cds[NN];
  int tid = threadIdx.x, lane = tid & 63, wv = tid >> 6;
  int p0 = blockIdx.x * 8, b = p0 >> 11;
  for (int j = tid; j < NN; j += 512)
    cds[j] = *(const float4*)&coordsT[((size_t)(b << 11) + j) * 4];
  __syncthreads();
  int p = p0 + wv, n = p & (NN - 1);
  float4 cc = cds[n];
  float sqi = __fadd_rn(__fadd_rn(__fmul_rn(cc.x, cc.x), __fmul_rn(cc.y, cc.y)),
                        __fmul_rn(cc.z, cc.z));
  ull t[16];
#pragma unroll
  for (int i = 0; i < 16; ++i) t[i] = ~0ull;
  for (int s = 0; s < 32; ++s) {
    int j = (s << 6) | lane;
    float4 q = cds[j];
    float sqj = __fadd_rn(__fadd_rn(__fmul_rn(q.x, q.x), __fmul_rn(q.y, q.y)),
                          __fmul_rn(q.z, q.z));
    float dt  = __fadd_rn(__fadd_rn(__fmul_rn(cc.x, q.x), __fmul_rn(cc.y, q.y)),
                          __fmul_rn(cc.z, q.z));
    float d2 = __fsub_rn(__fadd_rn(sqi, sqj), __fmul_rn(2.f, dt));
    unsigned u = __float_as_uint(d2);
    u = (u & 0x80000000u) ? ~u : (u | 0x80000000u);
    ull key = ((ull)u << 32) | (unsigned)j;
    if (key < t[15]) {
      t[15] = key;
#pragma unroll
      for (int i = 15; i > 0; --i) {
        ull lo = t[i - 1] < t[i] ? t[i - 1] : t[i];
        ull hi = t[i - 1] < t[i] ? t[i] : t[i - 1];
        t[i - 1] = lo; t[i] = hi;
      }
    }
  }
  for (int r = 0; r < KNB; ++r) {
    ull h = t[0];
    ull m = h;
#pragma unroll
    for (int off = 1; off < 64; off <<= 1) {
      ull o = __shfl_xor(m, off);
      m = o < m ? o : m;
    }
    if (lane == 0) idxout[(size_t)p * KNB + r] = (int)(m & 0xffffffffu);
    if (h == m) {
#pragma unroll
      for (int i = 0; i < 15; ++i) t[i] = t[i + 1];
      t[15] = ~0ull;
    }
  }
}

// ---------- MFMA fused kNN attention: shuffle-free softmax/epilogue via HT logit stash ----------
#define SMEM_BYTES 72192
__global__ __launch_bounds__(512, 4) void attn_mfma(
    const bf16* __restrict__ centerT, const bf16* __restrict__ gatherT,
    const float* __restrict__ coordsT, const bf16* __restrict__ vfeatT,
    const int* __restrict__ idx,
    const bf16* __restrict__ w1img, const bf16* __restrict__ w2img,
    const bf16* __restrict__ cw2img, const float* __restrict__ fb,
    bf16* __restrict__ aggT) {
  extern __shared__ char smem[];
  bf16* XS  = (bf16*)(smem);            // [128][132]
  bf16* HT  = (bf16*)(smem + 33792);    // [128][132]
  bf16* HC  = HT;                       // [128][68] aliases HT (dead before chunk 0)
  bf16* CFE = (bf16*)(smem + 67584);    // [8][128]
  bf16* VF  = (bf16*)(smem + 69632);    // [8][128]
  int*  NID = (int*)(smem + 71680);     // [128]
  const float* ab1f = fb;
  const float* ab2f = fb + 512;
  const float* cb1f = fb + 640;
  const float* cb2f = fb + 704;
  const float* cw1f = fb + 832;

  int tid = threadIdx.x, lane = tid & 63, wv = tid >> 6;
  int hl = lane >> 5, cA = lane & 31;
  int P0 = blockIdx.x * 8, b = P0 >> 11;

  if (tid < 128) NID[tid] = (b << 11) + idx[(size_t)(P0 + (tid >> 4)) * KNB + (tid & 15)];
  for (int i = tid; i < 1024; i += 512) {
    int g = i >> 7, d = i & 127;
    CFE[i] = centerT[(size_t)(P0 + g) * 128 + d];
    VF[i]  = vfeatT[(size_t)(P0 + g) * 128 + d];
  }
  __syncthreads();

  // phase 1: coord hidden HC + XS base (= cfe - gathered)
  {
    int m = tid >> 2, sub = tid & 3;
    float4 ccd = *(const float4*)&coordsT[(size_t)(P0 + (m >> 4)) * 4];
    float4 nbd = *(const float4*)&coordsT[(size_t)NID[m] * 4];
    float r0 = ccd.x - nbd.x, r1 = ccd.y - nbd.y, r2 = ccd.z - nbd.z;
    int h0 = sub * 16;
    for (int hh = h0; hh < h0 + 16; hh += 4) {
      float a0 = fmaxf(cb1f[hh+0] + cw1f[(hh+0)*3]*r0 + cw1f[(hh+0)*3+1]*r1 + cw1f[(hh+0)*3+2]*r2, 0.f);
      float a1 = fmaxf(cb1f[hh+1] + cw1f[(hh+1)*3]*r0 + cw1f[(hh+1)*3+1]*r1 + cw1f[(hh+1)*3+2]*r2, 0.f);
      float a2 = fmaxf(cb1f[hh+2] + cw1f[(hh+2)*3]*r0 + cw1f[(hh+2)*3+1]*r1 + cw1f[(hh+2)*3+2]*r2, 0.f);
      float a3 = fmaxf(cb1f[hh+3] + cw1f[(hh+3)*3]*r0 + cw1f[(hh+3)*3+1]*r1 + cw1f[(hh+3)*3+2]*r2, 0.f);
      *(long*)&HC[m * 68 + hh] = pack4(a0, a1, a2, a3);
    }
    const bf16* grow = gatherT + (size_t)NID[m] * 128 + sub * 32;
    const bf16* crow = CFE + ((m >> 4) << 7) + sub * 32;
    for (int j = 0; j < 32; j += 4) {
      float gv[4], cv[4];
      unpack4(*(const long*)(grow + j), gv);
      unpack4(*(const long*)(crow + j), cv);
      *(long*)&XS[m * 132 + sub * 32 + j] =
          pack4(cv[0] - gv[0], cv[1] - gv[1], cv[2] - gv[2], cv[3] - gv[3]);
    }
  }
  __syncthreads();

  int r0s = (wv & 3) * 32;     // output-row strip (o / h)
  int mt0 = (wv >> 2) * 64;    // token strip (2 tiles of 32)

  // preload chunk-0 W1 fragments (in flight across the emb GEMM)
  short8 pf[8];
#pragma unroll
  for (int ks = 0; ks < 8; ++ks)
    pf[ks] = ldfrag(w1img, r0s + cA, 132, ks * 16, hl);

  // phase 2: emb GEMM (C_e[o][m] = cw2 @ HC + cb2), RMW into XS
  {
    f32x16 eacc[2];
#pragma unroll
    for (int r = 0; r < 16; ++r) {
      int o = r0s + (r & 3) + 8 * (r >> 2) + 4 * hl;
      float bv = cb2f[o];
      eacc[0][r] = bv; eacc[1][r] = bv;
    }
    for (int k0 = 0; k0 < 64; k0 += 16) {
      short8 af = ldfrag(cw2img, r0s + cA, 68, k0, hl);   // global, L2-hot
      short8 b0 = ldfrag(HC, mt0 + cA, 68, k0, hl);
      short8 b1 = ldfrag(HC, mt0 + 32 + cA, 68, k0, hl);
      eacc[0] = MFMA(af, b0, eacc[0]);
      eacc[1] = MFMA(af, b1, eacc[1]);
    }
#pragma unroll
    for (int t = 0; t < 2; ++t) {
      int m = mt0 + t * 32 + cA;
#pragma unroll
      for (int q = 0; q < 4; ++q) {
        int ob = r0s + 8 * q + 4 * hl;
        bf16* px = &XS[m * 132 + ob];
        float xv[4];
        unpack4(*(long*)px, xv);
        *(long*)px = pack4(xv[0] + eacc[t][4*q+0], xv[1] + eacc[t][4*q+1],
                           xv[2] + eacc[t][4*q+2], xv[3] + eacc[t][4*q+3]);
      }
    }
  }
  __syncthreads();

  // logits accumulator (bias-init)
  f32x16 acc2[2];
#pragma unroll
  for (int r = 0; r < 16; ++r) {
    int o = r0s + (r & 3) + 8 * (r >> 2) + 4 * hl;
    float bv = ab2f[o];
    acc2[0][r] = bv; acc2[1][r] = bv;
  }

  // chunk loop: 4 x 128 hidden; pf[] rotates W1(chunk ac) -> W2(ac) -> W1(ac+1)
  for (int ac = 0; ac < 4; ++ac) {
    const bf16* w2c = w2img + (size_t)ac * 16896;
    const bf16* w1n = w1img + (size_t)((ac + 1) & 3) * 16896;
    f32x16 acc1[2];
#pragma unroll
    for (int r = 0; r < 16; ++r) {
      int h = r0s + (r & 3) + 8 * (r >> 2) + 4 * hl;
      float bv = ab1f[ac * 128 + h];
      acc1[0][r] = bv; acc1[1][r] = bv;
    }
#pragma unroll
    for (int ks = 0; ks < 8; ++ks) {
      short8 af = pf[ks];
      short8 b0 = ldfrag(XS, mt0 + cA, 132, ks * 16, hl);
      short8 b1 = ldfrag(XS, mt0 + 32 + cA, 132, ks * 16, hl);
      pf[ks] = ldfrag(w2c, r0s + cA, 132, ks * 16, hl);
      acc1[0] = MFMA(af, b0, acc1[0]);
      acc1[1] = MFMA(af, b1, acc1[1]);
    }
    __syncthreads();
#pragma unroll
    for (int t = 0; t < 2; ++t) {
      int m = mt0 + t * 32 + cA;
#pragma unroll
      for (int q = 0; q < 4; ++q) {
        int hb = r0s + 8 * q + 4 * hl;
        *(long*)&HT[m * 132 + hb] =
            pack4(fmaxf(acc1[t][4*q+0], 0.f), fmaxf(acc1[t][4*q+1], 0.f),
                  fmaxf(acc1[t][4*q+2], 0.f), fmaxf(acc1[t][4*q+3], 0.f));
      }
    }
    __syncthreads();
#pragma unroll
    for (int ks = 0; ks < 8; ++ks) {
      short8 af = pf[ks];
      short8 b0 = ldfrag(HT, mt0 + cA, 132, ks * 16, hl);
      short8 b1 = ldfrag(HT, mt0 + 32 + cA, 132, ks * 16, hl);
      pf[ks] = ldfrag(w1n, r0s + cA, 132, ks * 16, hl);
      acc2[0] = MFMA(af, b0, acc2[0]);
      acc2[1] = MFMA(af, b1, acc2[1]);
    }
  }

  // stash logits into HT (bf16, [m][o] layout) -- HT dead after last GEMM2
  __syncthreads();
#pragma unroll
  for (int t = 0; t < 2; ++t) {
    int m = mt0 + t * 32 + cA;
#pragma unroll
    for (int q = 0; q < 4; ++q) {
      int ob = r0s + 8 * q + 4 * hl;
      *(long*)&HT[m * 132 + ob] = pack4(acc2[t][4*q+0], acc2[t][4*q+1],
                                        acc2[t][4*q+2], acc2[t][4*q+3]);
    }
  }
  __syncthreads();

  // shuffle-free softmax-one + aggregation: wave wv owns point g=wv; lane owns o, o+64
  {
    int g = wv;
    int base = g * 16;
    float vbase0 = b2f(VF[g * 128 + lane])      - b2f(CFE[g * 128 + lane]);
    float vbase1 = b2f(VF[g * 128 + lane + 64]) - b2f(CFE[g * 128 + lane + 64]);
#pragma unroll
    for (int half = 0; half < 2; ++half) {
      int o = lane + half * 64;
      float vb = half ? vbase1 : vbase0;
      float e[16];
      float mx = -3.4e38f;
#pragma unroll
      for (int kk = 0; kk < 16; ++kk) {
        float x = b2f(HT[(base + kk) * 132 + o]);
        e[kk] = x;
        mx = fmaxf(mx, x);
      }
      float s = 0.f;
#pragma unroll
      for (int kk = 0; kk < 16; ++kk) { e[kk] = __expf(e[kk] - mx); s += e[kk]; }
      float inv = 1.f / (1.f + s);
      float acc = 0.f;
#pragma unroll
      for (int kk = 0; kk < 16; ++kk) {
        float xv = b2f(XS[(base + kk) * 132 + o]);
        float gv = b2f(gatherT[(size_t)NID[base + kk] * 128 + o]);
        acc += (e[kk] * inv) * (vb + xv + gv);
      }
      aggT[(size_t)(P0 + g) * 128 + o] = f2b(acc);
    }
  }
}

extern "C" void kernel_launch(void* const* d_in, const int* in_sizes, int n_in,
                              void* d_out, int out_size, void* d_ws, size_t ws_size,
                              hipStream_t stream) {
  // workspace layout
  int* flags = (int*)d_ws;
  bf16* catT = (bf16*)((float*)d_ws + 64);        // P x 256
  bf16* v0   = catT + (size_t)PP * 256;
  bf16* kT   = v0 + (size_t)PP * 128;
  bf16* qT   = kT + (size_t)PP * 128;
  bf16* sE   = qT + (size_t)PP * 128;             // vT, then value2
  bf16* sF   = sE + (size_t)PP * 128;             // tmp, agg1, agg2
  bf16* sG   = sF + (size_t)PP * 128;             // shortb, val1
  float* xyzT = (float*)(sG + (size_t)PP * 128);  // P x 4
  float* posT = xyzT + (size_t)PP * 4;
  int* idxb = (int*)(posT + (size_t)PP * 4);      // P x 16
  bf16* w1i1 = (bf16*)(idxb + (size_t)PP * KNB);  // 4*128*132
  bf16* w2i1 = w1i1 + 67584;
  bf16* cw2i1 = w2i1 + 67584;                     // 128*68
  bf16* w1i2 = cw2i1 + 8704;
  bf16* w2i2 = w1i2 + 67584;
  bf16* cw2i2 = w2i2 + 67584;
  float* fb1 = (float*)(cw2i2 + 8704);            // 1024 floats
  float* fb2 = fb1 + 1024;
  bf16* warena = (bf16*)(fb2 + 1024);             // 163840 bf16
  float* barena = (float*)(warena + 163840);      // 1024 fp32

  PtrArr pa;
  for (int i = 0; i < 36; ++i) { pa.p[i] = d_in[i]; pa.n[i] = in_sizes[i]; }
  sniff_kern<<<dim3(36), 256, 0, stream>>>(pa, flags);

  CvtTab tab;
  int wsrc[8] = {4, 8, 6, 10, 12, 14, 32, 34};
  int woff[8] = {0, 32768, 65536, 81920, 98304, 114688, 131072, 147456};
  int wn[8]   = {32768, 32768, 16384, 16384, 16384, 16384, 16384, 16384};
  int bsrc[8] = {5, 9, 7, 11, 13, 15, 33, 35};
  for (int e = 0; e < 8; ++e) {
    tab.src[e] = wsrc[e]; tab.off[e] = woff[e]; tab.n[e] = wn[e]; tab.isb[e] = 0;
    tab.src[8 + e] = bsrc[e]; tab.off[8 + e] = e * 128; tab.n[8 + e] = 128; tab.isb[8 + e] = 1;
  }
  cvtprep_kern<<<dim3(548, 18), 256, 0, stream>>>(pa, tab, flags, warena, barena,
                                                  w1i1, w2i1, cw2i1, fb1,
                                                  w1i2, w2i2, cw2i2, fb2);

  trall_kern<<<dim3(768), 256, 0, stream>>>(d_in[2], d_in[3], d_in[0], d_in[1],
                                            flags, catT, xyzT, posT);

  // fused frontend: mv_w1 -> sF(relu), mv_ws -> sG, wk -> kT, wq -> qT
  G4 g4;
  g4.X[0] = catT;       g4.K[0] = 256; g4.woff[0] = 0;      g4.boff[0] = 0;   g4.out[0] = sF; g4.relu[0] = 1;
  g4.X[1] = catT;       g4.K[1] = 256; g4.woff[1] = 32768;  g4.boff[1] = 128; g4.out[1] = sG; g4.relu[1] = 0;
  g4.X[2] = catT;       g4.K[2] = 128; g4.woff[2] = 81920;  g4.boff[2] = 384; g4.out[2] = kT; g4.relu[2] = 0;
  g4.X[3] = catT + 128; g4.K[3] = 128; g4.woff[3] = 98304;  g4.boff[3] = 512; g4.out[3] = qT; g4.relu[3] = 0;
  gemm4_kern<<<dim3(PP / 64, 4), 256, 0, stream>>>(g4, warena, barena);

  dim3 g32(PP / 32);
  gemm32_kern<<<g32, 256, 0, stream>>>(sF, warena + 65536,  barena + 256, sG,      v0, 0, nullptr, flags);
  gemm32_kern<<<g32, 256, 0, stream>>>(v0, warena + 114688, barena + 640, nullptr, sE, 0, nullptr, flags);

  hipFuncSetAttribute((const void*)attn_mfma, hipFuncAttributeMaxDynamicSharedMemorySize, SMEM_BYTES);

  // block 1 (xyz): center=k, gathered=q, vfeat=v
  knn_kern<<<dim3(PP / 8), 512, 0, stream>>>(xyzT, idxb);
  attn_mfma<<<dim3(PP / 8), 512, SMEM_BYTES, stream>>>(kT, qT, xyzT, sE, idxb,
                                                       w1i1, w2i1, cw2i1, fb1, sF);
  gemm32_kern<<<g32, 256, 0, stream>>>(sF, warena + 131072, barena + 768, v0,      sG, 0, nullptr, flags);
  gemm32_kern<<<g32, 256, 0, stream>>>(sG, warena + 114688, barena + 640, nullptr, sE, 0, nullptr, flags);
  // block 2 (pos): center=q, gathered=k, vfeat=value2
  knn_kern<<<dim3(PP / 8), 512, 0, stream>>>(posT, idxb);
  attn_mfma<<<dim3(PP / 8), 512, SMEM_BYTES, stream>>>(qT, kT, posT, sE, idxb,
                                                       w1i2, w2i2, cw2i2, fb2, sF);
  // final: wend + identity, writes d_out directly in (B,128,N) layout
  gemm32_kern<<<g32, 256, 0, stream>>>(sF, warena + 147456, barena + 896, v0, nullptr, 0, d_out, flags);
}

// Round 11
// 392.888 us; speedup vs baseline: 1.5228x; 1.1965x over previous
//
#include <hip/hip_runtime.h>
#include <hip/hip_bf16.h>

typedef __hip_bfloat16 bf16;
typedef unsigned long long ull;

#define BB 4
#define NN 2048
#define CCH 128
#define DDM 128
#define KNB 16
#define HHD 64
#define AAD 512
#define PP (BB*NN)

typedef __attribute__((ext_vector_type(8))) short short8;
typedef __attribute__((ext_vector_type(16))) float f32x16;

__device__ __forceinline__ float b2f(bf16 x) { return __bfloat162float(x); }
__device__ __forceinline__ bf16 f2b(float x) { return __float2bfloat16(x); }

__device__ __forceinline__ float ldany(const void* p, size_t i, int f32) {
  return f32 ? ((const float*)p)[i] : __bfloat162float(((const bf16*)p)[i]);
}

__device__ __forceinline__ long pack4(float a, float b, float c, float d) {
  union { bf16 h[4]; long l; } u;
  u.h[0] = f2b(a); u.h[1] = f2b(b); u.h[2] = f2b(c); u.h[3] = f2b(d);
  return u.l;
}
__device__ __forceinline__ void unpack4(long l, float* o) {
  union { bf16 h[4]; long l; } u; u.l = l;
  o[0] = b2f(u.h[0]); o[1] = b2f(u.h[1]); o[2] = b2f(u.h[2]); o[3] = b2f(u.h[3]);
}

__device__ __forceinline__ short8 ldfrag(const bf16* base, int row, int stride, int k0, int hl) {
  const bf16* p = base + (size_t)row * stride + k0 + (hl << 3);
  union { short8 v; long l[2]; } u;
  u.l[0] = *(const long*)p;
  u.l[1] = *(const long*)(p + 4);
  return u.v;
}

__device__ __forceinline__ f32x16 MFMA(short8 a, short8 b, f32x16 c) {
  return __builtin_amdgcn_mfma_f32_32x32x16_bf16(a, b, c, 0, 0, 0);
}

struct PtrArr { const void* p[36]; int n[36]; };
struct CvtTab { int src[16]; int off[16]; int n[16]; int isb[16]; };
struct G4 { const bf16* X[4]; int K[4]; int woff[4]; int boff[4]; bf16* out[4]; int relu[4]; };

// ---------- dtype sniffer ----------
__global__ __launch_bounds__(256) void sniff_kern(PtrArr pa, int* __restrict__ flags) {
  int t = blockIdx.x;
  const bf16* x = (const bf16*)pa.p[t];
  int n = pa.n[t]; if (n > 4096) n = 4096;
  __shared__ int cnt;
  if (threadIdx.x == 0) cnt = 0;
  __syncthreads();
  int c = 0;
  for (int i = threadIdx.x; i < n; i += 256) {
    float v = fabsf(__bfloat162float(x[i]));
    if (v == 0.f || (v >= 1e-6f && v <= 1024.f)) c++;
  }
  atomicAdd(&cnt, c);
  __syncthreads();
  if (threadIdx.x == 0) flags[t] = (cnt >= (n * 7) / 8) ? 0 : 1;
}

// ---------- fused convert: y<2 -> attn weight images (set=y); y>=2 -> GEMM arena entry ----------
__global__ __launch_bounds__(256) void cvtprep_kern(PtrArr pa, CvtTab tab,
                                                    const int* __restrict__ flags,
                                                    bf16* __restrict__ warena, float* __restrict__ barena,
                                                    bf16* __restrict__ w1img0, bf16* __restrict__ w2img0,
                                                    bf16* __restrict__ cw2img0, float* __restrict__ fb0,
                                                    bf16* __restrict__ w1img1, bf16* __restrict__ w2img1,
                                                    bf16* __restrict__ cw2img1, float* __restrict__ fb1) {
  int y = blockIdx.y;
  if (y >= 2) {
    int e = y - 2;
    int i = blockIdx.x * 256 + threadIdx.x;
    if (i >= tab.n[e]) return;
    float v = ldany(pa.p[tab.src[e]], i, flags[tab.src[e]]);
    if (tab.isb[e]) barena[tab.off[e] + i] = v;
    else warena[tab.off[e] + i] = f2b(v);
    return;
  }
  int set = y;
  int cIdx = set ? 20 : 16, aIdx = set ? 28 : 24, dd = set ? 2 : 3;
  bf16* w1img = set ? w1img1 : w1img0;
  bf16* w2img = set ? w2img1 : w2img0;
  bf16* cw2img = set ? cw2img1 : cw2img0;
  float* fb = set ? fb1 : fb0;
  const void* cw1 = pa.p[cIdx];     const void* cb1 = pa.p[cIdx + 1];
  const void* cw2 = pa.p[cIdx + 2]; const void* cb2 = pa.p[cIdx + 3];
  const void* aw1 = pa.p[aIdx];     const void* ab1 = pa.p[aIdx + 1];
  const void* aw2 = pa.p[aIdx + 2]; const void* ab2 = pa.p[aIdx + 3];
  int i = blockIdx.x * 256 + threadIdx.x;
  const int fcw1 = flags[cIdx], fcb1 = flags[cIdx + 1];
  const int fcw2 = flags[cIdx + 2], fcb2 = flags[cIdx + 3];
  const int faw1 = flags[aIdx], fab1 = flags[aIdx + 1];
  const int faw2 = flags[aIdx + 2], fab2 = flags[aIdx + 3];
  float* ab1f = fb;          // 512
  float* ab2f = fb + 512;    // 128
  float* cb1f = fb + 640;    // 64
  float* cb2f = fb + 704;    // 128
  float* cw1f = fb + 832;    // 192
  if (i < 65536) {                       // w1img: [h_glob 512][132]
    int hg = i >> 7, c = i & 127;
    w1img[(size_t)hg * 132 + c] = f2b(ldany(aw1, i, faw1));
  } else if (i < 131072) {               // w2img: [ac*128+o][132] col=h_local
    int j = i - 65536;
    int o = j >> 9, hh = j & 511;
    int ac = hh >> 7, hloc = hh & 127;
    w2img[(size_t)(ac * 128 + o) * 132 + hloc] = f2b(ldany(aw2, j, faw2));
  } else if (i < 139264) {               // cw2img: [o 128][68]
    int j = i - 131072;
    int o = j >> 6, h = j & 63;
    cw2img[o * 68 + h] = f2b(ldany(cw2, j, fcw2));
  } else if (i < 139776) {
    int j = i - 139264; ab1f[j] = ldany(ab1, j, fab1);
  } else if (i < 139904) {
    int j = i - 139776; ab2f[j] = ldany(ab2, j, fab2);
  } else if (i < 139968) {
    int j = i - 139904; cb1f[j] = ldany(cb1, j, fcb1);
  } else if (i < 140096) {
    int j = i - 139968; cb2f[j] = ldany(cb2, j, fcb2);
  } else if (i < 140288) {
    int j = i - 140096;
    int h = j / 3, c = j % 3;
    cw1f[j] = (c < dd) ? ldany(cw1, h * dd + c, fcw1) : 0.f;
  }
}

// ---------- fused transpose: x<512 key/query -> catT; x>=512 coords -> xyzT/posT ----------
__global__ __launch_bounds__(256) void trall_kern(const void* __restrict__ keyp,
                                                  const void* __restrict__ qryp,
                                                  const void* __restrict__ xyzp,
                                                  const void* __restrict__ posp,
                                                  const int* __restrict__ flags,
                                                  bf16* __restrict__ catT,
                                                  float* __restrict__ xyzT,
                                                  float* __restrict__ posT) {
  int bx = blockIdx.x;
  if (bx < 512) {
    __shared__ float tile[64][65];
    int xx = bx & 31, yy = (bx >> 5) & 1, zz = bx >> 6;
    int b = zz & 3, half = zz >> 2;
    const void* src = half ? qryp : keyp;
    const int f32 = flags[2 + half];
    int n0 = xx * 64, c0 = yy * 64;
    int tx = threadIdx.x & 63, ty = threadIdx.x >> 6;
    for (int r = ty; r < 64; r += 4)
      tile[r][tx] = ldany(src, (size_t)(b * 128 + c0 + r) * NN + n0 + tx, f32);
    __syncthreads();
    for (int r = ty; r < 64; r += 4)
      catT[(size_t)(b * NN + n0 + r) * 256 + half * 128 + c0 + tx] = __float2bfloat16(tile[tx][r]);
    return;
  }
  int cb = bx - 512;                 // 0..255
  int which = cb >> 7;               // 0: xyz, 1: pos
  const void* src = which ? posp : xyzp;
  float* dst = which ? posT : xyzT;
  int dd = which ? 2 : 3;
  const int f32 = flags[which];
  int i = (cb & 127) * 256 * 2 + threadIdx.x;
  for (int rep = 0; rep < 2; ++rep, i += 256) {
    if (i < PP * 4) {
      int p = i >> 2, j = i & 3;
      int b = p >> 11, n = p & (NN - 1);
      dst[i] = (j < dd) ? ldany(src, (size_t)(b * dd + j) * NN + n, f32) : 0.f;
    }
  }
}

// ---------- fused 4-op MFMA GEMM over catT (64 tokens x 128 outs, op=blockIdx.y) ----------
__global__ __launch_bounds__(256) void gemm4_kern(G4 g, const bf16* __restrict__ warena,
                                                  const float* __restrict__ barena) {
  __shared__ __attribute__((aligned(16))) bf16 XT[64 * 260];
  int op = blockIdx.y;
  const bf16* X = g.X[op];
  int K = g.K[op];
  const bf16* Wb = warena + g.woff[op];
  const float* bias = barena + g.boff[op];
  bf16* out = g.out[op];
  int relu = g.relu[op];
  int tid = threadIdx.x, lane = tid & 63, wv = tid >> 6;
  int hl = lane >> 5, cA = lane & 31;
  int p0 = blockIdx.x * 64;
  int SK = K + 4;
  int kc = K >> 3;
  for (int c = tid; c < 64 * kc; c += 256) {
    int r = c / kc, col = (c % kc) << 3;
    *(float4*)&XT[r * SK + col] = *(const float4*)&X[(size_t)(p0 + r) * 256 + col];
  }
  __syncthreads();
  int o0 = wv * 32;
  f32x16 acc[2];
#pragma unroll
  for (int r = 0; r < 16; ++r) {
    int o = o0 + (r & 3) + 8 * (r >> 2) + 4 * hl;
    float bv = bias[o];
    acc[0][r] = bv; acc[1][r] = bv;
  }
  for (int ks = 0; ks < (K >> 4); ++ks) {
    short8 af = ldfrag(Wb, o0 + cA, K, ks * 16, hl);
    short8 b0 = ldfrag(XT, cA, SK, ks * 16, hl);
    short8 b1 = ldfrag(XT, 32 + cA, SK, ks * 16, hl);
    acc[0] = MFMA(af, b0, acc[0]);
    acc[1] = MFMA(af, b1, acc[1]);
  }
#pragma unroll
  for (int t = 0; t < 2; ++t) {
    int m = p0 + t * 32 + cA;
#pragma unroll
    for (int q = 0; q < 4; ++q) {
      int ob = o0 + 8 * q + 4 * hl;
      float v[4] = {acc[t][4*q+0], acc[t][4*q+1], acc[t][4*q+2], acc[t][4*q+3]};
      if (relu) {
        v[0] = fmaxf(v[0], 0.f); v[1] = fmaxf(v[1], 0.f);
        v[2] = fmaxf(v[2], 0.f); v[3] = fmaxf(v[3], 0.f);
      }
      *(long*)(out + (size_t)m * 128 + ob) = pack4(v[0], v[1], v[2], v[3]);
    }
  }
}

// ---------- standalone MFMA GEMM: 32 tokens x 128 outs (K=128) ----------
__global__ __launch_bounds__(256) void gemm32_kern(
    const bf16* __restrict__ X,
    const bf16* __restrict__ Wb, const float* __restrict__ bias,
    const bf16* __restrict__ add, bf16* __restrict__ out, int relu,
    void* __restrict__ outT, const int* __restrict__ flags) {
  __shared__ __attribute__((aligned(16))) bf16 XT[32 * 132];
  int tid = threadIdx.x, lane = tid & 63, wv = tid >> 6;
  int hl = lane >> 5, cA = lane & 31;
  int p0 = blockIdx.x * 32;
  for (int c = tid; c < 32 * 16; c += 256) {
    int r = c >> 4, col = (c & 15) << 3;
    *(float4*)&XT[r * 132 + col] = *(const float4*)&X[(size_t)(p0 + r) * 128 + col];
  }
  __syncthreads();
  int o0 = wv * 32;
  f32x16 acc;
#pragma unroll
  for (int r = 0; r < 16; ++r) {
    int o = o0 + (r & 3) + 8 * (r >> 2) + 4 * hl;
    acc[r] = bias[o];
  }
#pragma unroll
  for (int ks = 0; ks < 8; ++ks) {
    short8 af = ldfrag(Wb, o0 + cA, 128, ks * 16, hl);
    short8 b0 = ldfrag(XT, cA, 132, ks * 16, hl);
    acc = MFMA(af, b0, acc);
  }
  int m = p0 + cA;
  int f32o = outT ? flags[2] : 0;
  int b = m >> 11, n = m & (NN - 1);
#pragma unroll
  for (int q = 0; q < 4; ++q) {
    int ob = o0 + 8 * q + 4 * hl;
    float v[4] = {acc[4*q+0], acc[4*q+1], acc[4*q+2], acc[4*q+3]};
    if (add) {
      float av[4];
      unpack4(*(const long*)(add + (size_t)m * 128 + ob), av);
      v[0] += av[0]; v[1] += av[1]; v[2] += av[2]; v[3] += av[3];
    }
    if (relu) {
      v[0] = fmaxf(v[0], 0.f); v[1] = fmaxf(v[1], 0.f);
      v[2] = fmaxf(v[2], 0.f); v[3] = fmaxf(v[3], 0.f);
    }
    if (outT) {
#pragma unroll
      for (int i = 0; i < 4; ++i) {
        size_t oi = (size_t)(b * 128 + ob + i) * NN + n;
        if (f32o) ((float*)outT)[oi] = v[i];
        else ((bf16*)outT)[oi] = f2b(v[i]);
      }
    } else {
      *(long*)(out + (size_t)m * 128 + ob) = pack4(v[0], v[1], v[2], v[3]);
    }
  }
}

// ---------- kNN both sets: 8 points/block, branch-free bitonic-sort-32 selection ----------
// blockIdx.y selects coord set. Per lane: store all 32 candidate keys, one static
// 240-CE bitonic network (no divergent insertion chains), then the same wave merge.
__global__ __launch_bounds__(512) void knn_kern(const float* __restrict__ xyzT,
                                                const float* __restrict__ posT,
                                                int* __restrict__ idx1,
                                                int* __restrict__ idx2) {
  __shared__ __attribute__((aligned(16))) float4 cds[NN];
  const float* coordsT = blockIdx.y ? posT : xyzT;
  int* idxout = blockIdx.y ? idx2 : idx1;
  int tid = threadIdx.x, lane = tid & 63, wv = tid >> 6;
  int p0 = blockIdx.x * 8, b = p0 >> 11;
  for (int j = tid; j < NN; j += 512)
    cds[j] = *(const float4*)&coordsT[((size_t)(b << 11) + j) * 4];
  __syncthreads();
  int p = p0 + wv, n = p & (NN - 1);
  float4 cc = cds[n];
  float sqi = __fadd_rn(__fadd_rn(__fmul_rn(cc.x, cc.x), __fmul_rn(cc.y, cc.y)),
                        __fmul_rn(cc.z, cc.z));
  ull t[32];
#pragma unroll
  for (int s = 0; s < 32; ++s) {
    int j = (s << 6) | lane;
    float4 q = cds[j];
    float sqj = __fadd_rn(__fadd_rn(__fmul_rn(q.x, q.x), __fmul_rn(q.y, q.y)),
                          __fmul_rn(q.z, q.z));
    float dt  = __fadd_rn(__fadd_rn(__fmul_rn(cc.x, q.x), __fmul_rn(cc.y, q.y)),
                          __fmul_rn(cc.z, q.z));
    float d2 = __fsub_rn(__fadd_rn(sqi, sqj), __fmul_rn(2.f, dt));
    unsigned u = __float_as_uint(d2);
    u = (u & 0x80000000u) ? ~u : (u | 0x80000000u);   // sortable ascending
    t[s] = ((ull)u << 32) | (unsigned)j;
  }
  // branch-free bitonic sort of 32 keys (ascending)
#pragma unroll
  for (int k = 2; k <= 32; k <<= 1) {
#pragma unroll
    for (int j = k >> 1; j > 0; j >>= 1) {
#pragma unroll
      for (int i = 0; i < 32; ++i) {
        int l = i ^ j;
        if (l > i) {
          bool up = ((i & k) == 0);
          ull a = t[i], c = t[l];
          ull lo = a < c ? a : c;
          ull hi = a < c ? c : a;
          t[i] = up ? lo : hi;
          t[l] = up ? hi : lo;
        }
      }
    }
  }
  // merge 64 sorted lists: 16 rounds of wave-min on heads (uses t[0..15] only)
  for (int r = 0; r < KNB; ++r) {
    ull h = t[0];
    ull m = h;
#pragma unroll
    for (int off = 1; off < 64; off <<= 1) {
      ull o = __shfl_xor(m, off);
      m = o < m ? o : m;
    }
    if (lane == 0) idxout[(size_t)p * KNB + r] = (int)(m & 0xffffffffu);
    if (h == m) {   // unique keys -> exactly one owner pops its head
#pragma unroll
      for (int i = 0; i < 15; ++i) t[i] = t[i + 1];
      t[15] = ~0ull;
    }
  }
}

// ---------- MFMA fused kNN attention: shuffle-free softmax/epilogue via HT logit stash ----------
#define SMEM_BYTES 72192
__global__ __launch_bounds__(512, 4) void attn_mfma(
    const bf16* __restrict__ centerT, const bf16* __restrict__ gatherT,
    const float* __restrict__ coordsT, const bf16* __restrict__ vfeatT,
    const int* __restrict__ idx,
    const bf16* __restrict__ w1img, const bf16* __restrict__ w2img,
    const bf16* __restrict__ cw2img, const float* __restrict__ fb,
    bf16* __restrict__ aggT) {
  extern __shared__ char smem[];
  bf16* XS  = (bf16*)(smem);            // [128][132]
  bf16* HT  = (bf16*)(smem + 33792);    // [128][132]
  bf16* HC  = HT;                       // [128][68] aliases HT (dead before chunk 0)
  bf16* CFE = (bf16*)(smem + 67584);    // [8][128]
  bf16* VF  = (bf16*)(smem + 69632);    // [8][128]
  int*  NID = (int*)(smem + 71680);     // [128]
  const float* ab1f = fb;
  const float* ab2f = fb + 512;
  const float* cb1f = fb + 640;
  const float* cb2f = fb + 704;
  const float* cw1f = fb + 832;

  int tid = threadIdx.x, lane = tid & 63, wv = tid >> 6;
  int hl = lane >> 5, cA = lane & 31;
  int P0 = blockIdx.x * 8, b = P0 >> 11;

  if (tid < 128) NID[tid] = (b << 11) + idx[(size_t)(P0 + (tid >> 4)) * KNB + (tid & 15)];
  for (int i = tid; i < 1024; i += 512) {
    int g = i >> 7, d = i & 127;
    CFE[i] = centerT[(size_t)(P0 + g) * 128 + d];
    VF[i]  = vfeatT[(size_t)(P0 + g) * 128 + d];
  }
  __syncthreads();

  // phase 1: coord hidden HC + XS base (= cfe - gathered)
  {
    int m = tid >> 2, sub = tid & 3;
    float4 ccd = *(const float4*)&coordsT[(size_t)(P0 + (m >> 4)) * 4];
    float4 nbd = *(const float4*)&coordsT[(size_t)NID[m] * 4];
    float r0 = ccd.x - nbd.x, r1 = ccd.y - nbd.y, r2 = ccd.z - nbd.z;
    int h0 = sub * 16;
    for (int hh = h0; hh < h0 + 16; hh += 4) {
      float a0 = fmaxf(cb1f[hh+0] + cw1f[(hh+0)*3]*r0 + cw1f[(hh+0)*3+1]*r1 + cw1f[(hh+0)*3+2]*r2, 0.f);
      float a1 = fmaxf(cb1f[hh+1] + cw1f[(hh+1)*3]*r0 + cw1f[(hh+1)*3+1]*r1 + cw1f[(hh+1)*3+2]*r2, 0.f);
      float a2 = fmaxf(cb1f[hh+2] + cw1f[(hh+2)*3]*r0 + cw1f[(hh+2)*3+1]*r1 + cw1f[(hh+2)*3+2]*r2, 0.f);
      float a3 = fmaxf(cb1f[hh+3] + cw1f[(hh+3)*3]*r0 + cw1f[(hh+3)*3+1]*r1 + cw1f[(hh+3)*3+2]*r2, 0.f);
      *(long*)&HC[m * 68 + hh] = pack4(a0, a1, a2, a3);
    }
    const bf16* grow = gatherT + (size_t)NID[m] * 128 + sub * 32;
    const bf16* crow = CFE + ((m >> 4) << 7) + sub * 32;
    for (int j = 0; j < 32; j += 4) {
      float gv[4], cv[4];
      unpack4(*(const long*)(grow + j), gv);
      unpack4(*(const long*)(crow + j), cv);
      *(long*)&XS[m * 132 + sub * 32 + j] =
          pack4(cv[0] - gv[0], cv[1] - gv[1], cv[2] - gv[2], cv[3] - gv[3]);
    }
  }
  __syncthreads();

  int r0s = (wv & 3) * 32;     // output-row strip (o / h)
  int mt0 = (wv >> 2) * 64;    // token strip (2 tiles of 32)

  // preload chunk-0 W1 fragments (in flight across the emb GEMM)
  short8 pf[8];
#pragma unroll
  for (int ks = 0; ks < 8; ++ks)
    pf[ks] = ldfrag(w1img, r0s + cA, 132, ks * 16, hl);

  // phase 2: emb GEMM (C_e[o][m] = cw2 @ HC + cb2), RMW into XS
  {
    f32x16 eacc[2];
#pragma unroll
    for (int r = 0; r < 16; ++r) {
      int o = r0s + (r & 3) + 8 * (r >> 2) + 4 * hl;
      float bv = cb2f[o];
      eacc[0][r] = bv; eacc[1][r] = bv;
    }
    for (int k0 = 0; k0 < 64; k0 += 16) {
      short8 af = ldfrag(cw2img, r0s + cA, 68, k0, hl);   // global, L2-hot
      short8 b0 = ldfrag(HC, mt0 + cA, 68, k0, hl);
      short8 b1 = ldfrag(HC, mt0 + 32 + cA, 68, k0, hl);
      eacc[0] = MFMA(af, b0, eacc[0]);
      eacc[1] = MFMA(af, b1, eacc[1]);
    }
#pragma unroll
    for (int t = 0; t < 2; ++t) {
      int m = mt0 + t * 32 + cA;
#pragma unroll
      for (int q = 0; q < 4; ++q) {
        int ob = r0s + 8 * q + 4 * hl;
        bf16* px = &XS[m * 132 + ob];
        float xv[4];
        unpack4(*(long*)px, xv);
        *(long*)px = pack4(xv[0] + eacc[t][4*q+0], xv[1] + eacc[t][4*q+1],
                           xv[2] + eacc[t][4*q+2], xv[3] + eacc[t][4*q+3]);
      }
    }
  }
  __syncthreads();

  // logits accumulator (bias-init)
  f32x16 acc2[2];
#pragma unroll
  for (int r = 0; r < 16; ++r) {
    int o = r0s + (r & 3) + 8 * (r >> 2) + 4 * hl;
    float bv = ab2f[o];
    acc2[0][r] = bv; acc2[1][r] = bv;
  }

  // chunk loop: 4 x 128 hidden; pf[] rotates W1(chunk ac) -> W2(ac) -> W1(ac+1)
  for (int ac = 0; ac < 4; ++ac) {
    const bf16* w2c = w2img + (size_t)ac * 16896;
    const bf16* w1n = w1img + (size_t)((ac + 1) & 3) * 16896;
    f32x16 acc1[2];
#pragma unroll
    for (int r = 0; r < 16; ++r) {
      int h = r0s + (r & 3) + 8 * (r >> 2) + 4 * hl;
      float bv = ab1f[ac * 128 + h];
      acc1[0][r] = bv; acc1[1][r] = bv;
    }
#pragma unroll
    for (int ks = 0; ks < 8; ++ks) {
      short8 af = pf[ks];
      short8 b0 = ldfrag(XS, mt0 + cA, 132, ks * 16, hl);
      short8 b1 = ldfrag(XS, mt0 + 32 + cA, 132, ks * 16, hl);
      pf[ks] = ldfrag(w2c, r0s + cA, 132, ks * 16, hl);
      acc1[0] = MFMA(af, b0, acc1[0]);
      acc1[1] = MFMA(af, b1, acc1[1]);
    }
    __syncthreads();
#pragma unroll
    for (int t = 0; t < 2; ++t) {
      int m = mt0 + t * 32 + cA;
#pragma unroll
      for (int q = 0; q < 4; ++q) {
        int hb = r0s + 8 * q + 4 * hl;
        *(long*)&HT[m * 132 + hb] =
            pack4(fmaxf(acc1[t][4*q+0], 0.f), fmaxf(acc1[t][4*q+1], 0.f),
                  fmaxf(acc1[t][4*q+2], 0.f), fmaxf(acc1[t][4*q+3], 0.f));
      }
    }
    __syncthreads();
#pragma unroll
    for (int ks = 0; ks < 8; ++ks) {
      short8 af = pf[ks];
      short8 b0 = ldfrag(HT, mt0 + cA, 132, ks * 16, hl);
      short8 b1 = ldfrag(HT, mt0 + 32 + cA, 132, ks * 16, hl);
      pf[ks] = ldfrag(w1n, r0s + cA, 132, ks * 16, hl);
      acc2[0] = MFMA(af, b0, acc2[0]);
      acc2[1] = MFMA(af, b1, acc2[1]);
    }
  }

  // stash logits into HT (bf16, [m][o] layout) -- HT dead after last GEMM2
  __syncthreads();
#pragma unroll
  for (int t = 0; t < 2; ++t) {
    int m = mt0 + t * 32 + cA;
#pragma unroll
    for (int q = 0; q < 4; ++q) {
      int ob = r0s + 8 * q + 4 * hl;
      *(long*)&HT[m * 132 + ob] = pack4(acc2[t][4*q+0], acc2[t][4*q+1],
                                        acc2[t][4*q+2], acc2[t][4*q+3]);
    }
  }
  __syncthreads();

  // shuffle-free softmax-one + aggregation: wave wv owns point g=wv; lane owns o, o+64
  {
    int g = wv;
    int base = g * 16;
    float vbase0 = b2f(VF[g * 128 + lane])      - b2f(CFE[g * 128 + lane]);
    float vbase1 = b2f(VF[g * 128 + lane + 64]) - b2f(CFE[g * 128 + lane + 64]);
#pragma unroll
    for (int half = 0; half < 2; ++half) {
      int o = lane + half * 64;
      float vb = half ? vbase1 : vbase0;
      float e[16];
      float mx = -3.4e38f;
#pragma unroll
      for (int kk = 0; kk < 16; ++kk) {
        float x = b2f(HT[(base + kk) * 132 + o]);
        e[kk] = x;
        mx = fmaxf(mx, x);
      }
      float s = 0.f;
#pragma unroll
      for (int kk = 0; kk < 16; ++kk) { e[kk] = __expf(e[kk] - mx); s += e[kk]; }
      float inv = 1.f / (1.f + s);
      float acc = 0.f;
#pragma unroll
      for (int kk = 0; kk < 16; ++kk) {
        float xv = b2f(XS[(base + kk) * 132 + o]);
        float gv = b2f(gatherT[(size_t)NID[base + kk] * 128 + o]);
        acc += (e[kk] * inv) * (vb + xv + gv);
      }
      aggT[(size_t)(P0 + g) * 128 + o] = f2b(acc);
    }
  }
}

extern "C" void kernel_launch(void* const* d_in, const int* in_sizes, int n_in,
                              void* d_out, int out_size, void* d_ws, size_t ws_size,
                              hipStream_t stream) {
  // workspace layout
  int* flags = (int*)d_ws;
  bf16* catT = (bf16*)((float*)d_ws + 64);        // P x 256
  bf16* v0   = catT + (size_t)PP * 256;
  bf16* kT   = v0 + (size_t)PP * 128;
  bf16* qT   = kT + (size_t)PP * 128;
  bf16* sE   = qT + (size_t)PP * 128;             // vT, then value2
  bf16* sF   = sE + (size_t)PP * 128;             // tmp, agg1, agg2
  bf16* sG   = sF + (size_t)PP * 128;             // shortb, val1
  float* xyzT = (float*)(sG + (size_t)PP * 128);  // P x 4
  float* posT = xyzT + (size_t)PP * 4;
  int* idx1 = (int*)(posT + (size_t)PP * 4);      // P x 16
  int* idx2 = idx1 + (size_t)PP * KNB;            // P x 16
  bf16* w1i1 = (bf16*)(idx2 + (size_t)PP * KNB);  // 4*128*132
  bf16* w2i1 = w1i1 + 67584;
  bf16* cw2i1 = w2i1 + 67584;                     // 128*68
  bf16* w1i2 = cw2i1 + 8704;
  bf16* w2i2 = w1i2 + 67584;
  bf16* cw2i2 = w2i2 + 67584;
  float* fb1 = (float*)(cw2i2 + 8704);            // 1024 floats
  float* fb2 = fb1 + 1024;
  bf16* warena = (bf16*)(fb2 + 1024);             // 163840 bf16
  float* barena = (float*)(warena + 163840);      // 1024 fp32

  PtrArr pa;
  for (int i = 0; i < 36; ++i) { pa.p[i] = d_in[i]; pa.n[i] = in_sizes[i]; }
  sniff_kern<<<dim3(36), 256, 0, stream>>>(pa, flags);

  CvtTab tab;
  int wsrc[8] = {4, 8, 6, 10, 12, 14, 32, 34};
  int woff[8] = {0, 32768, 65536, 81920, 98304, 114688, 131072, 147456};
  int wn[8]   = {32768, 32768, 16384, 16384, 16384, 16384, 16384, 16384};
  int bsrc[8] = {5, 9, 7, 11, 13, 15, 33, 35};
  for (int e = 0; e < 8; ++e) {
    tab.src[e] = wsrc[e]; tab.off[e] = woff[e]; tab.n[e] = wn[e]; tab.isb[e] = 0;
    tab.src[8 + e] = bsrc[e]; tab.off[8 + e] = e * 128; tab.n[8 + e] = 128; tab.isb[8 + e] = 1;
  }
  cvtprep_kern<<<dim3(548, 18), 256, 0, stream>>>(pa, tab, flags, warena, barena,
                                                  w1i1, w2i1, cw2i1, fb1,
                                                  w1i2, w2i2, cw2i2, fb2);

  trall_kern<<<dim3(768), 256, 0, stream>>>(d_in[2], d_in[3], d_in[0], d_in[1],
                                            flags, catT, xyzT, posT);

  // both kNN sets in one dispatch (y = set)
  knn_kern<<<dim3(PP / 8, 2), 512, 0, stream>>>(xyzT, posT, idx1, idx2);

  // fused frontend: mv_w1 -> sF(relu), mv_ws -> sG, wk -> kT, wq -> qT
  G4 g4;
  g4.X[0] = catT;       g4.K[0] = 256; g4.woff[0] = 0;      g4.boff[0] = 0;   g4.out[0] = sF; g4.relu[0] = 1;
  g4.X[1] = catT;       g4.K[1] = 256; g4.woff[1] = 32768;  g4.boff[1] = 128; g4.out[1] = sG; g4.relu[1] = 0;
  g4.X[2] = catT;       g4.K[2] = 128; g4.woff[2] = 81920;  g4.boff[2] = 384; g4.out[2] = kT; g4.relu[2] = 0;
  g4.X[3] = catT + 128; g4.K[3] = 128; g4.woff[3] = 98304;  g4.boff[3] = 512; g4.out[3] = qT; g4.relu[3] = 0;
  gemm4_kern<<<dim3(PP / 64, 4), 256, 0, stream>>>(g4, warena, barena);

  dim3 g32(PP / 32);
  gemm32_kern<<<g32, 256, 0, stream>>>(sF, warena + 65536,  barena + 256, sG,      v0, 0, nullptr, flags);
  gemm32_kern<<<g32, 256, 0, stream>>>(v0, warena + 114688, barena + 640, nullptr, sE, 0, nullptr, flags);

  hipFuncSetAttribute((const void*)attn_mfma, hipFuncAttributeMaxDynamicSharedMemorySize, SMEM_BYTES);

  // block 1 (xyz): center=k, gathered=q, vfeat=v
  attn_mfma<<<dim3(PP / 8), 512, SMEM_BYTES, stream>>>(kT, qT, xyzT, sE, idx1,
                                                       w1i1, w2i1, cw2i1, fb1, sF);
  gemm32_kern<<<g32, 256, 0, stream>>>(sF, warena + 131072, barena + 768, v0,      sG, 0, nullptr, flags);
  gemm32_kern<<<g32, 256, 0, stream>>>(sG, warena + 114688, barena + 640, nullptr, sE, 0, nullptr, flags);
  // block 2 (pos): center=q, gathered=k, vfeat=value2
  attn_mfma<<<dim3(PP / 8), 512, SMEM_BYTES, stream>>>(qT, kT, posT, sE, idx2,
                                                       w1i2, w2i2, cw2i2, fb2, sF);
  // final: wend + identity, writes d_out directly in (B,128,N) layout
  gemm32_kern<<<g32, 256, 0, stream>>>(sF, warena + 147456, barena + 896, v0, nullptr, 0, d_out, flags);
}

// Round 12
// 378.131 us; speedup vs baseline: 1.5822x; 1.0390x over previous
//
#include <hip/hip_runtime.h>
#include <hip/hip_bf16.h>

typedef __hip_bfloat16 bf16;
typedef unsigned long long ull;

#define BB 4
#define NN 2048
#define CCH 128
#define DDM 128
#define KNB 16
#define HHD 64
#define AAD 512
#define PP (BB*NN)

typedef __attribute__((ext_vector_type(8))) short short8;
typedef __attribute__((ext_vector_type(16))) float f32x16;

__device__ __forceinline__ float b2f(bf16 x) { return __bfloat162float(x); }
__device__ __forceinline__ bf16 f2b(float x) { return __float2bfloat16(x); }

__device__ __forceinline__ float ldany(const void* p, size_t i, int f32) {
  return f32 ? ((const float*)p)[i] : __bfloat162float(((const bf16*)p)[i]);
}

__device__ __forceinline__ long pack4(float a, float b, float c, float d) {
  union { bf16 h[4]; long l; } u;
  u.h[0] = f2b(a); u.h[1] = f2b(b); u.h[2] = f2b(c); u.h[3] = f2b(d);
  return u.l;
}
__device__ __forceinline__ void unpack4(long l, float* o) {
  union { bf16 h[4]; long l; } u; u.l = l;
  o[0] = b2f(u.h[0]); o[1] = b2f(u.h[1]); o[2] = b2f(u.h[2]); o[3] = b2f(u.h[3]);
}

__device__ __forceinline__ short8 ldfrag(const bf16* base, int row, int stride, int k0, int hl) {
  const bf16* p = base + (size_t)row * stride + k0 + (hl << 3);
  union { short8 v; long l[2]; } u;
  u.l[0] = *(const long*)p;
  u.l[1] = *(const long*)(p + 4);
  return u.v;
}

__device__ __forceinline__ f32x16 MFMA(short8 a, short8 b, f32x16 c) {
  return __builtin_amdgcn_mfma_f32_32x32x16_bf16(a, b, c, 0, 0, 0);
}

struct PtrArr { const void* p[36]; int n[36]; };
struct CvtTab { int src[16]; int off[16]; int n[16]; int isb[16]; };
struct G4 { const bf16* X[4]; int K[4]; int woff[4]; int boff[4]; bf16* out[4]; int relu[4]; };

// ---------- dtype sniffer ----------
__global__ __launch_bounds__(256) void sniff_kern(PtrArr pa, int* __restrict__ flags) {
  int t = blockIdx.x;
  const bf16* x = (const bf16*)pa.p[t];
  int n = pa.n[t]; if (n > 4096) n = 4096;
  __shared__ int cnt;
  if (threadIdx.x == 0) cnt = 0;
  __syncthreads();
  int c = 0;
  for (int i = threadIdx.x; i < n; i += 256) {
    float v = fabsf(__bfloat162float(x[i]));
    if (v == 0.f || (v >= 1e-6f && v <= 1024.f)) c++;
  }
  atomicAdd(&cnt, c);
  __syncthreads();
  if (threadIdx.x == 0) flags[t] = (cnt >= (n * 7) / 8) ? 0 : 1;
}

// ---------- fused convert: y<2 -> attn weight images (set=y); y>=2 -> GEMM arena entry ----------
__global__ __launch_bounds__(256) void cvtprep_kern(PtrArr pa, CvtTab tab,
                                                    const int* __restrict__ flags,
                                                    bf16* __restrict__ warena, float* __restrict__ barena,
                                                    bf16* __restrict__ w1img0, bf16* __restrict__ w2img0,
                                                    bf16* __restrict__ cw2img0, float* __restrict__ fb0,
                                                    bf16* __restrict__ w1img1, bf16* __restrict__ w2img1,
                                                    bf16* __restrict__ cw2img1, float* __restrict__ fb1) {
  int y = blockIdx.y;
  if (y >= 2) {
    int e = y - 2;
    int i = blockIdx.x * 256 + threadIdx.x;
    if (i >= tab.n[e]) return;
    float v = ldany(pa.p[tab.src[e]], i, flags[tab.src[e]]);
    if (tab.isb[e]) barena[tab.off[e] + i] = v;
    else warena[tab.off[e] + i] = f2b(v);
    return;
  }
  int set = y;
  int cIdx = set ? 20 : 16, aIdx = set ? 28 : 24, dd = set ? 2 : 3;
  bf16* w1img = set ? w1img1 : w1img0;
  bf16* w2img = set ? w2img1 : w2img0;
  bf16* cw2img = set ? cw2img1 : cw2img0;
  float* fb = set ? fb1 : fb0;
  const void* cw1 = pa.p[cIdx];     const void* cb1 = pa.p[cIdx + 1];
  const void* cw2 = pa.p[cIdx + 2]; const void* cb2 = pa.p[cIdx + 3];
  const void* aw1 = pa.p[aIdx];     const void* ab1 = pa.p[aIdx + 1];
  const void* aw2 = pa.p[aIdx + 2]; const void* ab2 = pa.p[aIdx + 3];
  int i = blockIdx.x * 256 + threadIdx.x;
  const int fcw1 = flags[cIdx], fcb1 = flags[cIdx + 1];
  const int fcw2 = flags[cIdx + 2], fcb2 = flags[cIdx + 3];
  const int faw1 = flags[aIdx], fab1 = flags[aIdx + 1];
  const int faw2 = flags[aIdx + 2], fab2 = flags[aIdx + 3];
  float* ab1f = fb;          // 512
  float* ab2f = fb + 512;    // 128
  float* cb1f = fb + 640;    // 64
  float* cb2f = fb + 704;    // 128
  float* cw1f = fb + 832;    // 192
  if (i < 65536) {                       // w1img: [h_glob 512][132]
    int hg = i >> 7, c = i & 127;
    w1img[(size_t)hg * 132 + c] = f2b(ldany(aw1, i, faw1));
  } else if (i < 131072) {               // w2img: [ac*128+o][132] col=h_local
    int j = i - 65536;
    int o = j >> 9, hh = j & 511;
    int ac = hh >> 7, hloc = hh & 127;
    w2img[(size_t)(ac * 128 + o) * 132 + hloc] = f2b(ldany(aw2, j, faw2));
  } else if (i < 139264) {               // cw2img: [o 128][68]
    int j = i - 131072;
    int o = j >> 6, h = j & 63;
    cw2img[o * 68 + h] = f2b(ldany(cw2, j, fcw2));
  } else if (i < 139776) {
    int j = i - 139264; ab1f[j] = ldany(ab1, j, fab1);
  } else if (i < 139904) {
    int j = i - 139776; ab2f[j] = ldany(ab2, j, fab2);
  } else if (i < 139968) {
    int j = i - 139904; cb1f[j] = ldany(cb1, j, fcb1);
  } else if (i < 140096) {
    int j = i - 139968; cb2f[j] = ldany(cb2, j, fcb2);
  } else if (i < 140288) {
    int j = i - 140096;
    int h = j / 3, c = j % 3;
    cw1f[j] = (c < dd) ? ldany(cw1, h * dd + c, fcw1) : 0.f;
  }
}

// ---------- fused transpose: x<512 key/query -> catT; x>=512 coords -> xyzT/posT ----------
__global__ __launch_bounds__(256) void trall_kern(const void* __restrict__ keyp,
                                                  const void* __restrict__ qryp,
                                                  const void* __restrict__ xyzp,
                                                  const void* __restrict__ posp,
                                                  const int* __restrict__ flags,
                                                  bf16* __restrict__ catT,
                                                  float* __restrict__ xyzT,
                                                  float* __restrict__ posT) {
  int bx = blockIdx.x;
  if (bx < 512) {
    __shared__ float tile[64][65];
    int xx = bx & 31, yy = (bx >> 5) & 1, zz = bx >> 6;
    int b = zz & 3, half = zz >> 2;
    const void* src = half ? qryp : keyp;
    const int f32 = flags[2 + half];
    int n0 = xx * 64, c0 = yy * 64;
    int tx = threadIdx.x & 63, ty = threadIdx.x >> 6;
    for (int r = ty; r < 64; r += 4)
      tile[r][tx] = ldany(src, (size_t)(b * 128 + c0 + r) * NN + n0 + tx, f32);
    __syncthreads();
    for (int r = ty; r < 64; r += 4)
      catT[(size_t)(b * NN + n0 + r) * 256 + half * 128 + c0 + tx] = __float2bfloat16(tile[tx][r]);
    return;
  }
  int cb = bx - 512;                 // 0..255
  int which = cb >> 7;               // 0: xyz, 1: pos
  const void* src = which ? posp : xyzp;
  float* dst = which ? posT : xyzT;
  int dd = which ? 2 : 3;
  const int f32 = flags[which];
  int i = (cb & 127) * 256 * 2 + threadIdx.x;
  for (int rep = 0; rep < 2; ++rep, i += 256) {
    if (i < PP * 4) {
      int p = i >> 2, j = i & 3;
      int b = p >> 11, n = p & (NN - 1);
      dst[i] = (j < dd) ? ldany(src, (size_t)(b * dd + j) * NN + n, f32) : 0.f;
    }
  }
}

// ---------- MEGA: bx<2048 -> kNN (both sets); bx>=2048 -> frontend gemm4 (512 thr) ----------
// Co-dispatched so the VALU-bound kNN blocks and MFMA-bound GEMM blocks overlap pipes.
__global__ __launch_bounds__(512) void mega_kern(
    const float* __restrict__ xyzT, const float* __restrict__ posT,
    int* __restrict__ idx1, int* __restrict__ idx2,
    G4 g, const bf16* __restrict__ warena, const float* __restrict__ barena) {
  __shared__ __attribute__((aligned(16))) char smem[33280];
  int bx = blockIdx.x;
  int tid = threadIdx.x, lane = tid & 63, wvv = tid >> 6;
  if (bx < 2048) {
    // ---- kNN path: 8 points/block, bitonic-sort-32 + wave merge ----
    float4* cds = (float4*)smem;
    int set = bx >> 10;
    int pblk = bx & 1023;
    const float* coordsT = set ? posT : xyzT;
    int* idxout = set ? idx2 : idx1;
    int p0 = pblk * 8, b = p0 >> 11;
    for (int j = tid; j < NN; j += 512)
      cds[j] = *(const float4*)&coordsT[((size_t)(b << 11) + j) * 4];
    __syncthreads();
    int p = p0 + wvv, n = p & (NN - 1);
    float4 cc = cds[n];
    float sqi = __fadd_rn(__fadd_rn(__fmul_rn(cc.x, cc.x), __fmul_rn(cc.y, cc.y)),
                          __fmul_rn(cc.z, cc.z));
    ull t[32];
#pragma unroll
    for (int s = 0; s < 32; ++s) {
      int j = (s << 6) | lane;
      float4 q = cds[j];
      float sqj = __fadd_rn(__fadd_rn(__fmul_rn(q.x, q.x), __fmul_rn(q.y, q.y)),
                            __fmul_rn(q.z, q.z));
      float dt  = __fadd_rn(__fadd_rn(__fmul_rn(cc.x, q.x), __fmul_rn(cc.y, q.y)),
                            __fmul_rn(cc.z, q.z));
      float d2 = __fsub_rn(__fadd_rn(sqi, sqj), __fmul_rn(2.f, dt));
      unsigned u = __float_as_uint(d2);
      u = (u & 0x80000000u) ? ~u : (u | 0x80000000u);   // sortable ascending
      t[s] = ((ull)u << 32) | (unsigned)j;
    }
    // branch-free bitonic sort of 32 keys (ascending)
#pragma unroll
    for (int k = 2; k <= 32; k <<= 1) {
#pragma unroll
      for (int j = k >> 1; j > 0; j >>= 1) {
#pragma unroll
        for (int i = 0; i < 32; ++i) {
          int l = i ^ j;
          if (l > i) {
            bool up = ((i & k) == 0);
            ull a = t[i], c = t[l];
            ull lo = a < c ? a : c;
            ull hi = a < c ? c : a;
            t[i] = up ? lo : hi;
            t[l] = up ? hi : lo;
          }
        }
      }
    }
    for (int r = 0; r < KNB; ++r) {
      ull h = t[0];
      ull m = h;
#pragma unroll
      for (int off = 1; off < 64; off <<= 1) {
        ull o = __shfl_xor(m, off);
        m = o < m ? o : m;
      }
      if (lane == 0) idxout[(size_t)p * KNB + r] = (int)(m & 0xffffffffu);
      if (h == m) {
#pragma unroll
        for (int i = 0; i < 15; ++i) t[i] = t[i + 1];
        t[15] = ~0ull;
      }
    }
    return;
  }
  // ---- gemm4 path: 64 tokens x 128 outs, 8 waves (one 32x32 tile each) ----
  {
    bf16* XT = (bf16*)smem;
    int bx2 = bx - 2048;
    int op = bx2 >> 7, ptile = bx2 & 127;
    const bf16* X = g.X[op];
    int K = g.K[op];
    const bf16* Wb = warena + g.woff[op];
    const float* bias = barena + g.boff[op];
    bf16* out = g.out[op];
    int relu = g.relu[op];
    int hl = lane >> 5, cA = lane & 31;
    int p0 = ptile * 64;
    int SK = K + 4;
    int kc = K >> 3;
    for (int c = tid; c < 64 * kc; c += 512) {
      int r = c / kc, col = (c % kc) << 3;
      *(float4*)&XT[r * SK + col] = *(const float4*)&X[(size_t)(p0 + r) * 256 + col];
    }
    __syncthreads();
    int o0 = (wvv & 3) * 32;
    int tt = wvv >> 2;
    f32x16 acc;
#pragma unroll
    for (int r = 0; r < 16; ++r) {
      int o = o0 + (r & 3) + 8 * (r >> 2) + 4 * hl;
      acc[r] = bias[o];
    }
    for (int ks = 0; ks < (K >> 4); ++ks) {
      short8 af = ldfrag(Wb, o0 + cA, K, ks * 16, hl);
      short8 b0 = ldfrag(XT, tt * 32 + cA, SK, ks * 16, hl);
      acc = MFMA(af, b0, acc);
    }
    int m = p0 + tt * 32 + cA;
#pragma unroll
    for (int q = 0; q < 4; ++q) {
      int ob = o0 + 8 * q + 4 * hl;
      float v[4] = {acc[4*q+0], acc[4*q+1], acc[4*q+2], acc[4*q+3]};
      if (relu) {
        v[0] = fmaxf(v[0], 0.f); v[1] = fmaxf(v[1], 0.f);
        v[2] = fmaxf(v[2], 0.f); v[3] = fmaxf(v[3], 0.f);
      }
      *(long*)(out + (size_t)m * 128 + ob) = pack4(v[0], v[1], v[2], v[3]);
    }
  }
}

// ---------- chained MFMA GEMM: Y1 = X·W1^T + b1 (+add1) [-> out1?]; out2 = Y1·W2^T + b2 ----------
__global__ __launch_bounds__(256) void gemm_chain_kern(
    const bf16* __restrict__ X, const bf16* __restrict__ warena,
    const float* __restrict__ barena,
    int w1off, int b1off, const bf16* __restrict__ add1, bf16* __restrict__ out1,
    int w2off, int b2off, bf16* __restrict__ out2) {
  __shared__ __attribute__((aligned(16))) bf16 XT[32 * 132];
  __shared__ __attribute__((aligned(16))) bf16 YT[32 * 132];
  int tid = threadIdx.x, lane = tid & 63, wv = tid >> 6;
  int hl = lane >> 5, cA = lane & 31;
  int p0 = blockIdx.x * 32;
  for (int c = tid; c < 32 * 16; c += 256) {
    int r = c >> 4, col = (c & 15) << 3;
    *(float4*)&XT[r * 132 + col] = *(const float4*)&X[(size_t)(p0 + r) * 128 + col];
  }
  __syncthreads();
  int o0 = wv * 32;
  const bf16* W1 = warena + w1off;
  const float* b1 = barena + b1off;
  f32x16 acc;
#pragma unroll
  for (int r = 0; r < 16; ++r) {
    int o = o0 + (r & 3) + 8 * (r >> 2) + 4 * hl;
    acc[r] = b1[o];
  }
#pragma unroll
  for (int ks = 0; ks < 8; ++ks) {
    short8 af = ldfrag(W1, o0 + cA, 128, ks * 16, hl);
    short8 b0 = ldfrag(XT, cA, 132, ks * 16, hl);
    acc = MFMA(af, b0, acc);
  }
  int m = p0 + cA;
#pragma unroll
  for (int q = 0; q < 4; ++q) {
    int ob = o0 + 8 * q + 4 * hl;
    float v[4] = {acc[4*q+0], acc[4*q+1], acc[4*q+2], acc[4*q+3]};
    if (add1) {
      float av[4];
      unpack4(*(const long*)(add1 + (size_t)m * 128 + ob), av);
      v[0] += av[0]; v[1] += av[1]; v[2] += av[2]; v[3] += av[3];
    }
    long pk = pack4(v[0], v[1], v[2], v[3]);
    *(long*)&YT[cA * 132 + ob] = pk;
    if (out1) *(long*)(out1 + (size_t)m * 128 + ob) = pk;
  }
  __syncthreads();
  const bf16* W2 = warena + w2off;
  const float* b2 = barena + b2off;
  f32x16 acc2;
#pragma unroll
  for (int r = 0; r < 16; ++r) {
    int o = o0 + (r & 3) + 8 * (r >> 2) + 4 * hl;
    acc2[r] = b2[o];
  }
#pragma unroll
  for (int ks = 0; ks < 8; ++ks) {
    short8 af = ldfrag(W2, o0 + cA, 128, ks * 16, hl);
    short8 b0 = ldfrag(YT, cA, 132, ks * 16, hl);
    acc2 = MFMA(af, b0, acc2);
  }
#pragma unroll
  for (int q = 0; q < 4; ++q) {
    int ob = o0 + 8 * q + 4 * hl;
    *(long*)(out2 + (size_t)m * 128 + ob) =
        pack4(acc2[4*q+0], acc2[4*q+1], acc2[4*q+2], acc2[4*q+3]);
  }
}

// ---------- standalone MFMA GEMM: 32 tokens x 128 outs (K=128); outT -> (B,128,N) ----------
__global__ __launch_bounds__(256) void gemm32_kern(
    const bf16* __restrict__ X,
    const bf16* __restrict__ Wb, const float* __restrict__ bias,
    const bf16* __restrict__ add, bf16* __restrict__ out, int relu,
    void* __restrict__ outT, const int* __restrict__ flags) {
  __shared__ __attribute__((aligned(16))) bf16 XT[32 * 132];
  int tid = threadIdx.x, lane = tid & 63, wv = tid >> 6;
  int hl = lane >> 5, cA = lane & 31;
  int p0 = blockIdx.x * 32;
  for (int c = tid; c < 32 * 16; c += 256) {
    int r = c >> 4, col = (c & 15) << 3;
    *(float4*)&XT[r * 132 + col] = *(const float4*)&X[(size_t)(p0 + r) * 128 + col];
  }
  __syncthreads();
  int o0 = wv * 32;
  f32x16 acc;
#pragma unroll
  for (int r = 0; r < 16; ++r) {
    int o = o0 + (r & 3) + 8 * (r >> 2) + 4 * hl;
    acc[r] = bias[o];
  }
#pragma unroll
  for (int ks = 0; ks < 8; ++ks) {
    short8 af = ldfrag(Wb, o0 + cA, 128, ks * 16, hl);
    short8 b0 = ldfrag(XT, cA, 132, ks * 16, hl);
    acc = MFMA(af, b0, acc);
  }
  int m = p0 + cA;
  int f32o = outT ? flags[2] : 0;
  int b = m >> 11, n = m & (NN - 1);
#pragma unroll
  for (int q = 0; q < 4; ++q) {
    int ob = o0 + 8 * q + 4 * hl;
    float v[4] = {acc[4*q+0], acc[4*q+1], acc[4*q+2], acc[4*q+3]};
    if (add) {
      float av[4];
      unpack4(*(const long*)(add + (size_t)m * 128 + ob), av);
      v[0] += av[0]; v[1] += av[1]; v[2] += av[2]; v[3] += av[3];
    }
    if (relu) {
      v[0] = fmaxf(v[0], 0.f); v[1] = fmaxf(v[1], 0.f);
      v[2] = fmaxf(v[2], 0.f); v[3] = fmaxf(v[3], 0.f);
    }
    if (outT) {
#pragma unroll
      for (int i = 0; i < 4; ++i) {
        size_t oi = (size_t)(b * 128 + ob + i) * NN + n;
        if (f32o) ((float*)outT)[oi] = v[i];
        else ((bf16*)outT)[oi] = f2b(v[i]);
      }
    } else {
      *(long*)(out + (size_t)m * 128 + ob) = pack4(v[0], v[1], v[2], v[3]);
    }
  }
}

// ---------- MFMA fused kNN attention: shuffle-free softmax/epilogue via HT logit stash ----------
#define SMEM_BYTES 72192
__global__ __launch_bounds__(512, 4) void attn_mfma(
    const bf16* __restrict__ centerT, const bf16* __restrict__ gatherT,
    const float* __restrict__ coordsT, const bf16* __restrict__ vfeatT,
    const int* __restrict__ idx,
    const bf16* __restrict__ w1img, const bf16* __restrict__ w2img,
    const bf16* __restrict__ cw2img, const float* __restrict__ fb,
    bf16* __restrict__ aggT) {
  extern __shared__ char smem[];
  bf16* XS  = (bf16*)(smem);            // [128][132]
  bf16* HT  = (bf16*)(smem + 33792);    // [128][132]
  bf16* HC  = HT;                       // [128][68] aliases HT (dead before chunk 0)
  bf16* CFE = (bf16*)(smem + 67584);    // [8][128]
  bf16* VF  = (bf16*)(smem + 69632);    // [8][128]
  int*  NID = (int*)(smem + 71680);     // [128]
  const float* ab1f = fb;
  const float* ab2f = fb + 512;
  const float* cb1f = fb + 640;
  const float* cb2f = fb + 704;
  const float* cw1f = fb + 832;

  int tid = threadIdx.x, lane = tid & 63, wv = tid >> 6;
  int hl = lane >> 5, cA = lane & 31;
  int P0 = blockIdx.x * 8, b = P0 >> 11;

  if (tid < 128) NID[tid] = (b << 11) + idx[(size_t)(P0 + (tid >> 4)) * KNB + (tid & 15)];
  for (int i = tid; i < 1024; i += 512) {
    int g = i >> 7, d = i & 127;
    CFE[i] = centerT[(size_t)(P0 + g) * 128 + d];
    VF[i]  = vfeatT[(size_t)(P0 + g) * 128 + d];
  }
  __syncthreads();

  // phase 1: coord hidden HC + XS base (= cfe - gathered)
  {
    int m = tid >> 2, sub = tid & 3;
    float4 ccd = *(const float4*)&coordsT[(size_t)(P0 + (m >> 4)) * 4];
    float4 nbd = *(const float4*)&coordsT[(size_t)NID[m] * 4];
    float r0 = ccd.x - nbd.x, r1 = ccd.y - nbd.y, r2 = ccd.z - nbd.z;
    int h0 = sub * 16;
    for (int hh = h0; hh < h0 + 16; hh += 4) {
      float a0 = fmaxf(cb1f[hh+0] + cw1f[(hh+0)*3]*r0 + cw1f[(hh+0)*3+1]*r1 + cw1f[(hh+0)*3+2]*r2, 0.f);
      float a1 = fmaxf(cb1f[hh+1] + cw1f[(hh+1)*3]*r0 + cw1f[(hh+1)*3+1]*r1 + cw1f[(hh+1)*3+2]*r2, 0.f);
      float a2 = fmaxf(cb1f[hh+2] + cw1f[(hh+2)*3]*r0 + cw1f[(hh+2)*3+1]*r1 + cw1f[(hh+2)*3+2]*r2, 0.f);
      float a3 = fmaxf(cb1f[hh+3] + cw1f[(hh+3)*3]*r0 + cw1f[(hh+3)*3+1]*r1 + cw1f[(hh+3)*3+2]*r2, 0.f);
      *(long*)&HC[m * 68 + hh] = pack4(a0, a1, a2, a3);
    }
    const bf16* grow = gatherT + (size_t)NID[m] * 128 + sub * 32;
    const bf16* crow = CFE + ((m >> 4) << 7) + sub * 32;
    for (int j = 0; j < 32; j += 4) {
      float gv[4], cv[4];
      unpack4(*(const long*)(grow + j), gv);
      unpack4(*(const long*)(crow + j), cv);
      *(long*)&XS[m * 132 + sub * 32 + j] =
          pack4(cv[0] - gv[0], cv[1] - gv[1], cv[2] - gv[2], cv[3] - gv[3]);
    }
  }
  __syncthreads();

  int r0s = (wv & 3) * 32;     // output-row strip (o / h)
  int mt0 = (wv >> 2) * 64;    // token strip (2 tiles of 32)

  // preload chunk-0 W1 fragments (in flight across the emb GEMM)
  short8 pf[8];
#pragma unroll
  for (int ks = 0; ks < 8; ++ks)
    pf[ks] = ldfrag(w1img, r0s + cA, 132, ks * 16, hl);

  // phase 2: emb GEMM (C_e[o][m] = cw2 @ HC + cb2), RMW into XS
  {
    f32x16 eacc[2];
#pragma unroll
    for (int r = 0; r < 16; ++r) {
      int o = r0s + (r & 3) + 8 * (r >> 2) + 4 * hl;
      float bv = cb2f[o];
      eacc[0][r] = bv; eacc[1][r] = bv;
    }
    for (int k0 = 0; k0 < 64; k0 += 16) {
      short8 af = ldfrag(cw2img, r0s + cA, 68, k0, hl);   // global, L2-hot
      short8 b0 = ldfrag(HC, mt0 + cA, 68, k0, hl);
      short8 b1 = ldfrag(HC, mt0 + 32 + cA, 68, k0, hl);
      eacc[0] = MFMA(af, b0, eacc[0]);
      eacc[1] = MFMA(af, b1, eacc[1]);
    }
#pragma unroll
    for (int t = 0; t < 2; ++t) {
      int m = mt0 + t * 32 + cA;
#pragma unroll
      for (int q = 0; q < 4; ++q) {
        int ob = r0s + 8 * q + 4 * hl;
        bf16* px = &XS[m * 132 + ob];
        float xv[4];
        unpack4(*(long*)px, xv);
        *(long*)px = pack4(xv[0] + eacc[t][4*q+0], xv[1] + eacc[t][4*q+1],
                           xv[2] + eacc[t][4*q+2], xv[3] + eacc[t][4*q+3]);
      }
    }
  }
  __syncthreads();

  // logits accumulator (bias-init)
  f32x16 acc2[2];
#pragma unroll
  for (int r = 0; r < 16; ++r) {
    int o = r0s + (r & 3) + 8 * (r >> 2) + 4 * hl;
    float bv = ab2f[o];
    acc2[0][r] = bv; acc2[1][r] = bv;
  }

  // chunk loop: 4 x 128 hidden; pf[] rotates W1(chunk ac) -> W2(ac) -> W1(ac+1)
  for (int ac = 0; ac < 4; ++ac) {
    const bf16* w2c = w2img + (size_t)ac * 16896;
    const bf16* w1n = w1img + (size_t)((ac + 1) & 3) * 16896;
    f32x16 acc1[2];
#pragma unroll
    for (int r = 0; r < 16; ++r) {
      int h = r0s + (r & 3) + 8 * (r >> 2) + 4 * hl;
      float bv = ab1f[ac * 128 + h];
      acc1[0][r] = bv; acc1[1][r] = bv;
    }
#pragma unroll
    for (int ks = 0; ks < 8; ++ks) {
      short8 af = pf[ks];
      short8 b0 = ldfrag(XS, mt0 + cA, 132, ks * 16, hl);
      short8 b1 = ldfrag(XS, mt0 + 32 + cA, 132, ks * 16, hl);
      pf[ks] = ldfrag(w2c, r0s + cA, 132, ks * 16, hl);
      acc1[0] = MFMA(af, b0, acc1[0]);
      acc1[1] = MFMA(af, b1, acc1[1]);
    }
    __syncthreads();
#pragma unroll
    for (int t = 0; t < 2; ++t) {
      int m = mt0 + t * 32 + cA;
#pragma unroll
      for (int q = 0; q < 4; ++q) {
        int hb = r0s + 8 * q + 4 * hl;
        *(long*)&HT[m * 132 + hb] =
            pack4(fmaxf(acc1[t][4*q+0], 0.f), fmaxf(acc1[t][4*q+1], 0.f),
                  fmaxf(acc1[t][4*q+2], 0.f), fmaxf(acc1[t][4*q+3], 0.f));
      }
    }
    __syncthreads();
#pragma unroll
    for (int ks = 0; ks < 8; ++ks) {
      short8 af = pf[ks];
      short8 b0 = ldfrag(HT, mt0 + cA, 132, ks * 16, hl);
      short8 b1 = ldfrag(HT, mt0 + 32 + cA, 132, ks * 16, hl);
      pf[ks] = ldfrag(w1n, r0s + cA, 132, ks * 16, hl);
      acc2[0] = MFMA(af, b0, acc2[0]);
      acc2[1] = MFMA(af, b1, acc2[1]);
    }
  }

  // stash logits into HT (bf16, [m][o] layout) -- HT dead after last GEMM2
  __syncthreads();
#pragma unroll
  for (int t = 0; t < 2; ++t) {
    int m = mt0 + t * 32 + cA;
#pragma unroll
    for (int q = 0; q < 4; ++q) {
      int ob = r0s + 8 * q + 4 * hl;
      *(long*)&HT[m * 132 + ob] = pack4(acc2[t][4*q+0], acc2[t][4*q+1],
                                        acc2[t][4*q+2], acc2[t][4*q+3]);
    }
  }
  __syncthreads();

  // shuffle-free softmax-one + aggregation: wave wv owns point g=wv; lane owns o, o+64
  {
    int g = wv;
    int base = g * 16;
    float vbase0 = b2f(VF[g * 128 + lane])      - b2f(CFE[g * 128 + lane]);
    float vbase1 = b2f(VF[g * 128 + lane + 64]) - b2f(CFE[g * 128 + lane + 64]);
#pragma unroll
    for (int half = 0; half < 2; ++half) {
      int o = lane + half * 64;
      float vb = half ? vbase1 : vbase0;
      float e[16];
      float mx = -3.4e38f;
#pragma unroll
      for (int kk = 0; kk < 16; ++kk) {
        float x = b2f(HT[(base + kk) * 132 + o]);
        e[kk] = x;
        mx = fmaxf(mx, x);
      }
      float s = 0.f;
#pragma unroll
      for (int kk = 0; kk < 16; ++kk) { e[kk] = __expf(e[kk] - mx); s += e[kk]; }
      float inv = 1.f / (1.f + s);
      float acc = 0.f;
#pragma unroll
      for (int kk = 0; kk < 16; ++kk) {
        float xv = b2f(XS[(base + kk) * 132 + o]);
        float gv = b2f(gatherT[(size_t)NID[base + kk] * 128 + o]);
        acc += (e[kk] * inv) * (vb + xv + gv);
      }
      aggT[(size_t)(P0 + g) * 128 + o] = f2b(acc);
    }
  }
}

extern "C" void kernel_launch(void* const* d_in, const int* in_sizes, int n_in,
                              void* d_out, int out_size, void* d_ws, size_t ws_size,
                              hipStream_t stream) {
  // workspace layout
  int* flags = (int*)d_ws;
  bf16* catT = (bf16*)((float*)d_ws + 64);        // P x 256
  bf16* v0   = catT + (size_t)PP * 256;
  bf16* kT   = v0 + (size_t)PP * 128;
  bf16* qT   = kT + (size_t)PP * 128;
  bf16* sE   = qT + (size_t)PP * 128;             // vT, then value2
  bf16* sF   = sE + (size_t)PP * 128;             // tmp, agg1, agg2
  bf16* sG   = sF + (size_t)PP * 128;             // shortb
  float* xyzT = (float*)(sG + (size_t)PP * 128);  // P x 4
  float* posT = xyzT + (size_t)PP * 4;
  int* idx1 = (int*)(posT + (size_t)PP * 4);      // P x 16
  int* idx2 = idx1 + (size_t)PP * KNB;            // P x 16
  bf16* w1i1 = (bf16*)(idx2 + (size_t)PP * KNB);  // 4*128*132
  bf16* w2i1 = w1i1 + 67584;
  bf16* cw2i1 = w2i1 + 67584;                     // 128*68
  bf16* w1i2 = cw2i1 + 8704;
  bf16* w2i2 = w1i2 + 67584;
  bf16* cw2i2 = w2i2 + 67584;
  float* fb1 = (float*)(cw2i2 + 8704);            // 1024 floats
  float* fb2 = fb1 + 1024;
  bf16* warena = (bf16*)(fb2 + 1024);             // 163840 bf16
  float* barena = (float*)(warena + 163840);      // 1024 fp32

  PtrArr pa;
  for (int i = 0; i < 36; ++i) { pa.p[i] = d_in[i]; pa.n[i] = in_sizes[i]; }
  sniff_kern<<<dim3(36), 256, 0, stream>>>(pa, flags);

  CvtTab tab;
  int wsrc[8] = {4, 8, 6, 10, 12, 14, 32, 34};
  int woff[8] = {0, 32768, 65536, 81920, 98304, 114688, 131072, 147456};
  int wn[8]   = {32768, 32768, 16384, 16384, 16384, 16384, 16384, 16384};
  int bsrc[8] = {5, 9, 7, 11, 13, 15, 33, 35};
  for (int e = 0; e < 8; ++e) {
    tab.src[e] = wsrc[e]; tab.off[e] = woff[e]; tab.n[e] = wn[e]; tab.isb[e] = 0;
    tab.src[8 + e] = bsrc[e]; tab.off[8 + e] = e * 128; tab.n[8 + e] = 128; tab.isb[8 + e] = 1;
  }
  cvtprep_kern<<<dim3(548, 18), 256, 0, stream>>>(pa, tab, flags, warena, barena,
                                                  w1i1, w2i1, cw2i1, fb1,
                                                  w1i2, w2i2, cw2i2, fb2);

  trall_kern<<<dim3(768), 256, 0, stream>>>(d_in[2], d_in[3], d_in[0], d_in[1],
                                            flags, catT, xyzT, posT);

  // MEGA: kNN (both sets) co-dispatched with the 4-op frontend GEMM
  G4 g4;
  g4.X[0] = catT;       g4.K[0] = 256; g4.woff[0] = 0;      g4.boff[0] = 0;   g4.out[0] = sF; g4.relu[0] = 1;
  g4.X[1] = catT;       g4.K[1] = 256; g4.woff[1] = 32768;  g4.boff[1] = 128; g4.out[1] = sG; g4.relu[1] = 0;
  g4.X[2] = catT;       g4.K[2] = 128; g4.woff[2] = 81920;  g4.boff[2] = 384; g4.out[2] = kT; g4.relu[2] = 0;
  g4.X[3] = catT + 128; g4.K[3] = 128; g4.woff[3] = 98304;  g4.boff[3] = 512; g4.out[3] = qT; g4.relu[3] = 0;
  mega_kern<<<dim3(2048 + 512), 512, 0, stream>>>(xyzT, posT, idx1, idx2, g4, warena, barena);

  // chain 1: v0 = mv_w2·tmp + shortb (write v0); sE = wv·v0
  gemm_chain_kern<<<dim3(PP / 32), 256, 0, stream>>>(sF, warena, barena,
                                                     65536, 256, sG, v0,
                                                     114688, 640, sE);

  hipFuncSetAttribute((const void*)attn_mfma, hipFuncAttributeMaxDynamicSharedMemorySize, SMEM_BYTES);

  // block 1 (xyz): center=k, gathered=q, vfeat=v
  attn_mfma<<<dim3(PP / 8), 512, SMEM_BYTES, stream>>>(kT, qT, xyzT, sE, idx1,
                                                       w1i1, w2i1, cw2i1, fb1, sF);
  // chain 2: val1 = wkq·agg1 + v0 (LDS only); sE = wv·val1 (value2)
  gemm_chain_kern<<<dim3(PP / 32), 256, 0, stream>>>(sF, warena, barena,
                                                     131072, 768, v0, nullptr,
                                                     114688, 640, sE);
  // block 2 (pos): center=q, gathered=k, vfeat=value2
  attn_mfma<<<dim3(PP / 8), 512, SMEM_BYTES, stream>>>(qT, kT, posT, sE, idx2,
                                                       w1i2, w2i2, cw2i2, fb2, sF);
  // final: wend + identity, writes d_out directly in (B,128,N) layout
  gemm32_kern<<<dim3(PP / 32), 256, 0, stream>>>(sF, warena + 147456, barena + 896, v0,
                                                 nullptr, 0, d_out, flags);
}